// Round 9
// baseline (5297.317 us; speedup 1.0000x reference)
//
#include <hip/hip_runtime.h>
#include <hip/hip_bf16.h>

#define DEV static __device__ __forceinline__

typedef unsigned short u16;
typedef unsigned long long u64;
typedef __attribute__((ext_vector_type(8))) short short8;   // 8 bf16 (4 VGPRs) MFMA frag
typedef __attribute__((ext_vector_type(4))) float f32x4;    // MFMA accumulator

constexpr int V = 32000, H = 1024, B = 32, T = 256;
constexpr int BT = B * T;       // 8192 rows
constexpr int G  = 4 * H;       // 4096 gates
constexpr int NCH = V / 256;    // 125 col-chunks for softmax partials
constexpr int NWG3 = 96;        // persistent LSTM blocks (32 L0 + 64 L1)
constexpr int FSTR = 16;        // flag stride (ints) -> one 64B line per flag
constexpr int RSTRIDE = 32 * 2048 + 2048;  // u16 per h-buffer (132KB incl 4KB pad)

// ---------------- workspace layout (bytes) ----------------
constexpr size_t SZ_WT    = (size_t)G * 2048 * 2;            // [4096][2048] bf16
constexpr size_t OFF_W0T  = 0;
constexpr size_t OFF_W1T  = OFF_W0T + SZ_WT;
constexpr size_t OFF_EBF  = OFF_W1T + SZ_WT;                 // [32000][1024] bf16
constexpr size_t OFF_XBF  = OFF_EBF + (size_t)V * H * 2;     // [8192][1024] bf16 (row = t*32+b)
constexpr size_t OFF_XP0  = OFF_XBF + (size_t)BT * H * 2;    // bf16 perm [t][ub][wv][col16][b32]
constexpr size_t OFF_H1   = OFF_XP0 + (size_t)BT * G * 2;    // [8192][1024] bf16 (row = b*256+t)
constexpr size_t OFF_HSEQ = OFF_H1 + (size_t)BT * H * 2;     // R[0..T+1], write-once per tick
constexpr size_t SZ_HSEQ  = (size_t)(T + 2) * RSTRIDE * 2;
constexpr size_t OFF_SYNC = OFF_HSEQ + SZ_HSEQ;              // flags f0[256*32] f1[256*64], 64B ea
constexpr size_t SZ_SYNC  = (size_t)(256 * 32 + 256 * 64) * FSTR * 4;   // 1.5MB
constexpr size_t OFF_PMAX = OFF_SYNC + SZ_SYNC;              // [8192][125] f32
constexpr size_t OFF_PSUM = OFF_PMAX + (size_t)BT * NCH * 4;
constexpr size_t OFF_LOSS = OFF_PSUM + (size_t)BT * NCH * 4; // [8192] f32

DEV u16 f2bf(float x) {  // RNE f32 -> bf16 bits
  union { float f; unsigned int u; } v; v.f = x;
  unsigned int r = v.u + 0x7fffu + ((v.u >> 16) & 1u);
  return (u16)(r >> 16);
}
DEV float bf2f(u16 b) {
  union { unsigned int u; float f; } v; v.u = ((unsigned int)b) << 16;
  return v.f;
}
DEV float sigm(float x) { return 1.f / (1.f + expf(-x)); }

DEV void gload_lds16(const u16* g, u16* l) {
  __builtin_amdgcn_global_load_lds(
      (__attribute__((address_space(1))) void*)g,
      (__attribute__((address_space(3))) void*)l, 16, 0, 0);
}

// ---------------- prep kernels ----------------

__global__ void k_transpose_cvt(const float* __restrict__ in, u16* __restrict__ out,
                                int R, int C) {
  __shared__ float tile[32][33];
  int bc = blockIdx.x * 32, br = blockIdx.y * 32;
  int tx = threadIdx.x & 31, ty0 = threadIdx.x >> 5;
#pragma unroll
  for (int i = 0; i < 4; ++i) {
    int ty = ty0 + i * 8;
    tile[ty][tx] = in[(size_t)(br + ty) * C + bc + tx];
  }
  __syncthreads();
#pragma unroll
  for (int i = 0; i < 4; ++i) {
    int ty = ty0 + i * 8;
    out[(size_t)(bc + ty) * R + br + tx] = f2bf(tile[tx][ty]);
  }
}

__global__ void k_cvt_bf16(const float* __restrict__ in, u16* __restrict__ out, int n4) {
  int i = blockIdx.x * blockDim.x + threadIdx.x;
  int stride = gridDim.x * blockDim.x;
  for (; i < n4; i += stride) {
    float4 v = ((const float4*)in)[i];
    ushort4 o;
    o.x = f2bf(v.x); o.y = f2bf(v.y); o.z = f2bf(v.z); o.w = f2bf(v.w);
    ((ushort4*)out)[i] = o;
  }
}

__global__ void k_gather_x(const float* __restrict__ emb, const int* __restrict__ inp,
                           u16* __restrict__ Xbf) {
  int row = blockIdx.x;
  int t = row >> 5, b = row & 31;
  int tok = inp[b * T + t];
  const float4* src = (const float4*)(emb + (size_t)tok * H);
  ushort4* dst = (ushort4*)(Xbf + (size_t)row * H);
  float4 v = src[threadIdx.x];
  ushort4 o;
  o.x = f2bf(v.x); o.y = f2bf(v.y); o.z = f2bf(v.z); o.w = f2bf(v.w);
  dst[threadIdx.x] = o;
}

__global__ void k_zero(unsigned int* __restrict__ p, int nwords) {
  int i = blockIdx.x * blockDim.x + threadIdx.x;
  int stride = gridDim.x * blockDim.x;
  for (; i < nwords; i += stride) p[i] = 0u;
}

// ---------------- 128x128 bf16 MFMA GEMM (m97 structure, for xp0) --------
// CMODE 1: C bf16, permuted [t][ub(32)][wv(8)][col16 = q*4+u][b(32)].
template <int CMODE>
__global__ __launch_bounds__(256)
void k_gemm(const u16* __restrict__ A, int lda,
            const u16* __restrict__ Bt, int ldb,
            float* __restrict__ C, int ldc,
            const float* __restrict__ bias, int K) {
  __shared__ alignas(16) u16 ldsA[128 * 32];
  __shared__ alignas(16) u16 ldsB[128 * 32];

  unsigned nwg = gridDim.x * gridDim.y;
  unsigned flat = blockIdx.y * gridDim.x + blockIdx.x;
  unsigned nf = (flat & 7) * (nwg >> 3) + (flat >> 3);
  unsigned bx = nf % gridDim.x, by = nf / gridDim.x;

  int tid = threadIdx.x, lane = tid & 63, w = tid >> 6;
  int row0 = by * 128, col0 = bx * 128;
  int wr = w >> 1, wc = w & 1;
  int c15 = lane & 15, q4 = lane >> 4;

  const u16* ag[2]; const u16* bg[2];
#pragma unroll
  for (int j = 0; j < 2; ++j) {
    int r = (j * 4 + w) * 16 + (lane >> 2);
    int k = (lane & 3) * 8;
    ag[j] = A + (size_t)(row0 + r) * lda + k;
    bg[j] = Bt + (size_t)(col0 + r) * ldb + k;
  }
  u16* lA0 = ldsA + (size_t)(0 + w) * 512;
  u16* lA1 = ldsA + (size_t)(4 + w) * 512;
  u16* lB0 = ldsB + (size_t)(0 + w) * 512;
  u16* lB1 = ldsB + (size_t)(4 + w) * 512;

  f32x4 acc[4][4];
#pragma unroll
  for (int m = 0; m < 4; ++m)
#pragma unroll
    for (int n = 0; n < 4; ++n) acc[m][n] = (f32x4){0.f, 0.f, 0.f, 0.f};

  int nk = K >> 5;
  for (int kk = 0; kk < nk; ++kk) {
    int kb = kk * 32;
    gload_lds16(ag[0] + kb, lA0);
    gload_lds16(ag[1] + kb, lA1);
    gload_lds16(bg[0] + kb, lB0);
    gload_lds16(bg[1] + kb, lB1);
    __syncthreads();

    short8 af[4], bfr[4];
#pragma unroll
    for (int m = 0; m < 4; ++m)
      af[m] = *(const short8*)(ldsA + (wr * 64 + m * 16 + c15) * 32 + q4 * 8);
#pragma unroll
    for (int n = 0; n < 4; ++n)
      bfr[n] = *(const short8*)(ldsB + (wc * 64 + n * 16 + c15) * 32 + q4 * 8);
#pragma unroll
    for (int m = 0; m < 4; ++m)
#pragma unroll
      for (int n = 0; n < 4; ++n)
        acc[m][n] = __builtin_amdgcn_mfma_f32_16x16x32_bf16(af[m], bfr[n], acc[m][n], 0, 0, 0);
    __syncthreads();
  }

  float bias_n[4];
#pragma unroll
  for (int n = 0; n < 4; ++n) bias_n[n] = bias[col0 + wc * 64 + n * 16 + c15];

#pragma unroll
  for (int m = 0; m < 4; ++m) {
#pragma unroll
    for (int jr = 0; jr < 4; ++jr) {
      int r_g = row0 + wr * 64 + m * 16 + q4 * 4 + jr;
#pragma unroll
      for (int n = 0; n < 4; ++n) {
        int c_g = col0 + wc * 64 + n * 16 + c15;
        float val = acc[m][n][jr] + bias_n[n];
        if (CMODE == 0) {
          C[(size_t)r_g * ldc + c_g] = val;
        } else {
          // (t,b) from row; (q, ub, wv, u) from col; dest [t][ub][wv][q*4+u][b]
          int tt = r_g >> 5, bb = r_g & 31;
          int q = c_g >> 10, U = c_g & 1023;
          int ub = U >> 5, wvi = (U >> 2) & 7, uu = U & 3;
          ((u16*)C)[(((((size_t)tt * 32 + ub) * 8 + wvi) * 16 + q * 4 + uu) * 32) + bb]
              = f2bf(val);
        }
      }
    }
  }
}

// ---------------- 256x256 8-wave counted-vmcnt GEMM (logits) --------------
// BK=32, 96KB LDS 3-deep ring (slot t%3) -> staging tile t+2 never touches a
// buffer being read (fixes the 2-buffer WAR race). vmcnt(4) at tile end
// guarantees tile t+1 staged; never drains to 0 until the tail. XOR
// unit-swizzle on BOTH stage-source and frag-read (rule #21).
constexpr int GNT = 32;  // K-tiles (K=1024)

DEV void stage256(const u16* __restrict__ A, int lda,
                  const u16* __restrict__ Bt, int ldb,
                  int row0, int col0, u16* lds, int t, int h, int tid) {
  int op = h >> 1, hh = h & 1;
  int wid = tid >> 6, lane = tid & 63;
  int r = hh * 128 + wid * 16 + (lane >> 2);
  int k = t * 32 + (((lane & 3) ^ ((lane >> 2) & 3)) << 3);  // XOR unit-swizzle
  const u16* g = (op == 0) ? (A + (size_t)(row0 + r) * lda + k)
                           : (Bt + (size_t)(col0 + r) * ldb + k);
  u16* l = lds + (size_t)((op * 3 + (t % 3)) * 8192 + (hh * 128 + wid * 16) * 32);
  gload_lds16(g, l);
}

template <bool SM_EPI>
__global__ __launch_bounds__(512)
void k_gemm256(const u16* __restrict__ A, int lda,
               const u16* __restrict__ Bt, int ldb,
               float* __restrict__ C, int ldc,
               const float* __restrict__ bias,
               float* __restrict__ pmax, float* __restrict__ psum, int nch) {
  __shared__ alignas(16) u16 lds[6 * 8192];   // 96KB: [op(2)][slot(3)][256*32]

  unsigned nwg = gridDim.x * gridDim.y;       // 4000, %8==0
  unsigned flat = blockIdx.y * gridDim.x + blockIdx.x;
  unsigned nf = (flat & 7) * (nwg >> 3) + (flat >> 3);
  int bx = nf % gridDim.x, by = nf / gridDim.x;
  int row0 = by * 256, col0 = bx * 256;

  int tid = threadIdx.x, lane = tid & 63, wid = tid >> 6;
  int wr = wid >> 2, wc = wid & 3;            // 2M x 4N waves
  int c15 = lane & 15, q4 = lane >> 4;
  int usw = (q4 ^ (c15 & 3)) << 3;            // swizzled unit offset

  f32x4 acc[8][4];
#pragma unroll
  for (int m = 0; m < 8; ++m)
#pragma unroll
    for (int n = 0; n < 4; ++n) acc[m][n] = (f32x4){0.f, 0.f, 0.f, 0.f};

  // prologue: stage tiles 0 and 1 (4 halves each)
#pragma unroll
  for (int h = 0; h < 4; ++h) stage256(A, lda, Bt, ldb, row0, col0, lds, 0, h, tid);
#pragma unroll
  for (int h = 0; h < 4; ++h) stage256(A, lda, Bt, ldb, row0, col0, lds, 1, h, tid);
  asm volatile("s_waitcnt vmcnt(4)" ::: "memory");   // tile 0 staged
  __builtin_amdgcn_sched_barrier(0);
  __builtin_amdgcn_s_barrier();

  short8 af[4], bfr[4];

  for (int t = 0; t < GNT; ++t) {
    const u16* la = lds + (size_t)(t % 3) * 8192;
    const u16* lb = lds + (size_t)(3 + t % 3) * 8192;

    // ---- phase 0: m 0..3 ----
#pragma unroll
    for (int m = 0; m < 4; ++m)
      af[m] = *(const short8*)(la + (wr * 128 + m * 16 + c15) * 32 + usw);
#pragma unroll
    for (int n = 0; n < 4; ++n)
      bfr[n] = *(const short8*)(lb + (wc * 64 + n * 16 + c15) * 32 + usw);
    if (t + 2 < GNT) {
      stage256(A, lda, Bt, ldb, row0, col0, lds, t + 2, 0, tid);
      stage256(A, lda, Bt, ldb, row0, col0, lds, t + 2, 1, tid);
    }
    __builtin_amdgcn_s_barrier();
    asm volatile("s_waitcnt lgkmcnt(0)" ::: "memory");
    __builtin_amdgcn_sched_barrier(0);
    __builtin_amdgcn_s_setprio(1);
#pragma unroll
    for (int m = 0; m < 4; ++m)
#pragma unroll
      for (int n = 0; n < 4; ++n)
        acc[m][n] = __builtin_amdgcn_mfma_f32_16x16x32_bf16(af[m], bfr[n], acc[m][n], 0, 0, 0);
    __builtin_amdgcn_s_setprio(0);
    __builtin_amdgcn_s_barrier();

    // ---- phase 1: m 4..7 ----
#pragma unroll
    for (int m = 0; m < 4; ++m)
      af[m] = *(const short8*)(la + (wr * 128 + (m + 4) * 16 + c15) * 32 + usw);
    if (t + 2 < GNT) {
      stage256(A, lda, Bt, ldb, row0, col0, lds, t + 2, 2, tid);
      stage256(A, lda, Bt, ldb, row0, col0, lds, t + 2, 3, tid);
    }
    __builtin_amdgcn_s_barrier();
    asm volatile("s_waitcnt lgkmcnt(0)" ::: "memory");
    __builtin_amdgcn_sched_barrier(0);
    __builtin_amdgcn_s_setprio(1);
#pragma unroll
    for (int m = 0; m < 4; ++m)
#pragma unroll
      for (int n = 0; n < 4; ++n)
        acc[m + 4][n] = __builtin_amdgcn_mfma_f32_16x16x32_bf16(af[m], bfr[n], acc[m + 4][n], 0, 0, 0);
    __builtin_amdgcn_s_setprio(0);
    // counted vmcnt once per K-tile: tile t+1 (4 oldest) staged
    if (t < GNT - 2) {
      asm volatile("s_waitcnt vmcnt(4)" ::: "memory");
      __builtin_amdgcn_sched_barrier(0);
    } else if (t == GNT - 2) {
      asm volatile("s_waitcnt vmcnt(0)" ::: "memory");
      __builtin_amdgcn_sched_barrier(0);
    }
    __builtin_amdgcn_s_barrier();
  }

  // ---- epilogue: bias + C write + online-softmax partials ----
  float bias_n[4];
#pragma unroll
  for (int n = 0; n < 4; ++n) bias_n[n] = bias[col0 + wc * 64 + n * 16 + c15];

  float2* red = (float2*)lds;   // overlay [256][4]
  __syncthreads();

#pragma unroll
  for (int m = 0; m < 8; ++m) {
#pragma unroll
    for (int jr = 0; jr < 4; ++jr) {
      int rloc = wr * 128 + m * 16 + q4 * 4 + jr;
      int r_g = row0 + rloc;
      float v[4];
#pragma unroll
      for (int n = 0; n < 4; ++n) {
        int c_g = col0 + wc * 64 + n * 16 + c15;
        float val = acc[m][n][jr] + bias_n[n];
        C[(size_t)r_g * ldc + c_g] = val;
        v[n] = val;
      }
      if (SM_EPI) {
        float mx = fmaxf(fmaxf(v[0], v[1]), fmaxf(v[2], v[3]));
        float s = __expf(v[0] - mx) + __expf(v[1] - mx) + __expf(v[2] - mx) + __expf(v[3] - mx);
#pragma unroll
        for (int d = 1; d < 16; d <<= 1) {
          float mo = __shfl_xor(mx, d, 64);
          float so = __shfl_xor(s, d, 64);
          float M2 = fmaxf(mx, mo);
          s = s * __expf(mx - M2) + so * __expf(mo - M2);
          mx = M2;
        }
        if (c15 == 0) red[rloc * 4 + wc] = make_float2(mx, s);
      }
    }
  }
  if (SM_EPI) {
    __syncthreads();
    if (tid < 256) {
      float M = -1e30f, S = 0.f;
#pragma unroll
      for (int i = 0; i < 4; ++i) {
        float2 a = red[tid * 4 + i];
        float M2 = fmaxf(M, a.x);
        S = S * __expf(M - M2) + a.y * __expf(a.x - M2);
        M = M2;
      }
      pmax[(size_t)(row0 + tid) * nch + bx] = M;
      psum[(size_t)(row0 + tid) * nch + bx] = S;
    }
  }
}

// ---------------- persistent LSTM v2: wave-local gates ----------------
// 96 blocks x 512 thr. Blocks 0..31 = L0: wave owns 4 units x all 4 gates,
// full K=1024 in-wave (128 VGPR weights) -> NO cross-wave reduce, no barrier
// in the compute path. Blocks 32..95 = L1 (16 units each): wave pairs
// (wv, wv+4) split K=2048; one LDS merge + syncthreads.
// Sync: per-block write-once flag words (64B apart), per-wave polling.

DEV int flag_ld(const int* p) {
  return __hip_atomic_load(p, __ATOMIC_RELAXED, __HIP_MEMORY_SCOPE_AGENT);
}

DEV void wave_poll(const int* fa, int na, const int* fb) {  // fb: 64 flags or null
  int lane = threadIdx.x & 63;
  while (true) {
    int ok = 1;
    if (lane < na) ok = (flag_ld(fa + (size_t)lane * FSTR) != 0);
    if (fb) ok &= (flag_ld(fb + (size_t)lane * FSTR) != 0);
    if (__all(ok)) break;
    __builtin_amdgcn_s_sleep(1);
  }
}

__global__ __launch_bounds__(512, 2)
void k_lstm2(const u16* __restrict__ W0T, const u16* __restrict__ W1T,
             const u16* __restrict__ xp0p, const float* __restrict__ b1,
             u16* __restrict__ hseq, u16* __restrict__ H1bf,
             int* __restrict__ sync) {
  __shared__ float zlds[8][2][16][16];   // 16KB; per-wave (L0) / per pair-slot (L1)
  int wg = blockIdx.x;
  int tid = threadIdx.x, lane = tid & 63, wv = tid >> 6;
  int c15 = lane & 15, q4 = lane >> 4;
  int u = lane & 3, b0e = lane >> 2;     // epilogue identity: pairs p=lane, p=64+lane
  int* f0 = sync;                        // [256*32] stride FSTR
  int* f1 = sync + (size_t)256 * 32 * FSTR;  // [256*64] stride FSTR

  if (wg < 32) {
    // ================= layer 0 =================
    int ub = wg;
    int U0 = ub * 32 + wv * 4;
    short8 wfr[32];
    {
      int q = c15 >> 2, u4 = c15 & 3;
      const u16* rp = W0T + (size_t)(q * 1024 + U0 + u4) * 2048 + 1024 + q4 * 8;
#pragma unroll
      for (int ks = 0; ks < 32; ++ks) wfr[ks] = *(const short8*)(rp + ks * 32);
    }
    float cr0 = 0.f, cr1 = 0.f;

    for (int t = 0; t < T; ++t) {
      // bias prefetch (before flag wait, hides L3 latency)
      const u16* xb = xp0p + ((((size_t)t * 32 + ub) * 8 + wv) * 16) * 32;
      u16 zpb0[4], zpb1[4];
#pragma unroll
      for (int q = 0; q < 4; ++q) {
        zpb0[q] = xb[(q * 4 + u) * 32 + b0e];
        zpb1[q] = xb[(q * 4 + u) * 32 + b0e + 16];
      }
      if (t >= 1) wave_poll(f0 + (size_t)(t - 1) * 32 * FSTR, 32, nullptr);

      const u16* hread = hseq + (size_t)t * RSTRIDE;
      f32x4 acc0 = (f32x4){0.f, 0.f, 0.f, 0.f}, acc1 = (f32x4){0.f, 0.f, 0.f, 0.f};
      short8 af0[8], af1[8];
#pragma unroll
      for (int p = 0; p < 8; ++p) {
        af0[p] = *(const short8*)(hread + (size_t)c15 * 2048 + p * 32 + q4 * 8);
        af1[p] = *(const short8*)(hread + (size_t)(16 + c15) * 2048 + p * 32 + q4 * 8);
      }
#pragma unroll
      for (int ks = 0; ks < 32; ++ks) {
        int s = ks & 7;
        short8 a0 = af0[s], a1 = af1[s];
        if (ks < 24) {
          af0[s] = *(const short8*)(hread + (size_t)c15 * 2048 + (ks + 8) * 32 + q4 * 8);
          af1[s] = *(const short8*)(hread + (size_t)(16 + c15) * 2048 + (ks + 8) * 32 + q4 * 8);
        }
        acc0 = __builtin_amdgcn_mfma_f32_16x16x32_bf16(a0, wfr[ks], acc0, 0, 0, 0);
        acc1 = __builtin_amdgcn_mfma_f32_16x16x32_bf16(a1, wfr[ks], acc1, 0, 0, 0);
      }
      // per-wave LDS transpose (no block barrier: same-wave producer/consumer)
#pragma unroll
      for (int j = 0; j < 4; ++j) {
        zlds[wv][0][q4 * 4 + j][c15] = acc0[j];
        zlds[wv][1][q4 * 4 + j][c15] = acc1[j];
      }
      float hv0, hv1;
      {
        float z[4];
#pragma unroll
        for (int q = 0; q < 4; ++q)
          z[q] = zlds[wv][b0e >> 4][b0e & 15][q * 4 + u] + bf2f(zpb0[q]);
        float gi = sigm(z[0]), gj = tanhf(z[1]), gf = sigm(z[2] + 1.f), go = sigm(z[3]);
        cr0 = cr0 * gf + gi * gj;
        hv0 = go * tanhf(cr0);
      }
      {
        float z[4];
#pragma unroll
        for (int q = 0; q < 4; ++q)
          z[q] = zlds[wv][1][b0e & 15][q * 4 + u] + bf2f(zpb1[q]);
        float gi = sigm(z[0]), gj = tanhf(z[1]), gf = sigm(z[2] + 1.f), go = sigm(z[3]);
        cr1 = cr1 * gf + gi * gj;
        hv1 = go * tanhf(cr1);
      }
      int hb0 = (int)f2bf(hv0), hb1 = (int)f2bf(hv1);
      int hp0 = __shfl_xor(hb0, 1, 64), hp1 = __shfl_xor(hb1, 1, 64);
      if (!(lane & 1)) {
        u16* hwr = hseq + (size_t)(t + 1) * RSTRIDE;
        unsigned pk0 = (u16)hb0 | ((unsigned)(u16)hp0 << 16);
        unsigned pk1 = (u16)hb1 | ((unsigned)(u16)hp1 << 16);
        __hip_atomic_store((unsigned*)(hwr + (size_t)b0e * 2048 + U0 + u), pk0,
                           __ATOMIC_RELAXED, __HIP_MEMORY_SCOPE_AGENT);
        __hip_atomic_store((unsigned*)(hwr + (size_t)(b0e + 16) * 2048 + U0 + u), pk1,
                           __ATOMIC_RELAXED, __HIP_MEMORY_SCOPE_AGENT);
      }
      __syncthreads();   // drains all waves' vmcnt -> h visible, then publish
      if (tid == 0)
        __hip_atomic_store(f0 + ((size_t)t * 32 + ub) * FSTR, 1,
                           __ATOMIC_RELAXED, __HIP_MEMORY_SCOPE_AGENT);
    }
  } else {
    // ================= layer 1 =================
    int ub = wg - 32;                    // 0..63, 16 units each
    int grp = wv & 3, khalf = wv >> 2;
    int U0 = ub * 16 + grp * 4;
    short8 wfr[32];
    {
      int q = c15 >> 2, u4 = c15 & 3;
      const u16* rp = W1T + (size_t)(q * 1024 + U0 + u4) * 2048 + khalf * 1024 + q4 * 8;
#pragma unroll
      for (int ks = 0; ks < 32; ++ks) wfr[ks] = *(const short8*)(rp + ks * 32);
    }
    float zpc[4];
#pragma unroll
    for (int q = 0; q < 4; ++q) zpc[q] = b1[q * 1024 + U0 + u];
    float cr0 = 0.f, cr1 = 0.f;

    for (int t = 1; t <= T; ++t) {       // computes h1(t-1)
      wave_poll(f0 + (size_t)(t - 1) * 32 * FSTR, 32,
                t >= 2 ? f1 + (size_t)(t - 2) * 64 * FSTR : nullptr);

      const u16* hread = hseq + (size_t)t * RSTRIDE + khalf * 1024;
      f32x4 acc0 = (f32x4){0.f, 0.f, 0.f, 0.f}, acc1 = (f32x4){0.f, 0.f, 0.f, 0.f};
      short8 af0[8], af1[8];
#pragma unroll
      for (int p = 0; p < 8; ++p) {
        af0[p] = *(const short8*)(hread + (size_t)c15 * 2048 + p * 32 + q4 * 8);
        af1[p] = *(const short8*)(hread + (size_t)(16 + c15) * 2048 + p * 32 + q4 * 8);
      }
#pragma unroll
      for (int ks = 0; ks < 32; ++ks) {
        int s = ks & 7;
        short8 a0 = af0[s], a1 = af1[s];
        if (ks < 24) {
          af0[s] = *(const short8*)(hread + (size_t)c15 * 2048 + (ks + 8) * 32 + q4 * 8);
          af1[s] = *(const short8*)(hread + (size_t)(16 + c15) * 2048 + (ks + 8) * 32 + q4 * 8);
        }
        acc0 = __builtin_amdgcn_mfma_f32_16x16x32_bf16(a0, wfr[ks], acc0, 0, 0, 0);
        acc1 = __builtin_amdgcn_mfma_f32_16x16x32_bf16(a1, wfr[ks], acc1, 0, 0, 0);
      }
      // pair-slot partials
#pragma unroll
      for (int j = 0; j < 4; ++j) {
        zlds[grp * 2 + khalf][0][q4 * 4 + j][c15] = acc0[j];
        zlds[grp * 2 + khalf][1][q4 * 4 + j][c15] = acc1[j];
      }
      __syncthreads();
      if (khalf == 0) {
        float hv0, hv1;
        {
          float z[4];
#pragma unroll
          for (int q = 0; q < 4; ++q)
            z[q] = zlds[grp * 2][b0e >> 4][b0e & 15][q * 4 + u] +
                   zlds[grp * 2 + 1][b0e >> 4][b0e & 15][q * 4 + u] + zpc[q];
          float gi = sigm(z[0]), gj = tanhf(z[1]), gf = sigm(z[2] + 1.f), go = sigm(z[3]);
          cr0 = cr0 * gf + gi * gj;
          hv0 = go * tanhf(cr0);
        }
        {
          float z[4];
#pragma unroll
          for (int q = 0; q < 4; ++q)
            z[q] = zlds[grp * 2][1][b0e & 15][q * 4 + u] +
                   zlds[grp * 2 + 1][1][b0e & 15][q * 4 + u] + zpc[q];
          float gi = sigm(z[0]), gj = tanhf(z[1]), gf = sigm(z[2] + 1.f), go = sigm(z[3]);
          cr1 = cr1 * gf + gi * gj;
          hv1 = go * tanhf(cr1);
        }
        int hb0 = (int)f2bf(hv0), hb1 = (int)f2bf(hv1);
        int hp0 = __shfl_xor(hb0, 1, 64), hp1 = __shfl_xor(hb1, 1, 64);
        if (!(lane & 1)) {
          u16* hwr = hseq + (size_t)(t + 1) * RSTRIDE + 1024;
          unsigned pk0 = (u16)hb0 | ((unsigned)(u16)hp0 << 16);
          unsigned pk1 = (u16)hb1 | ((unsigned)(u16)hp1 << 16);
          __hip_atomic_store((unsigned*)(hwr + (size_t)b0e * 2048 + U0 + u), pk0,
                             __ATOMIC_RELAXED, __HIP_MEMORY_SCOPE_AGENT);
          __hip_atomic_store((unsigned*)(hwr + (size_t)(b0e + 16) * 2048 + U0 + u), pk1,
                             __ATOMIC_RELAXED, __HIP_MEMORY_SCOPE_AGENT);
          *(unsigned*)(H1bf + ((size_t)b0e * T + (t - 1)) * H + U0 + u) = pk0;
          *(unsigned*)(H1bf + ((size_t)(b0e + 16) * T + (t - 1)) * H + U0 + u) = pk1;
        }
      }
      __syncthreads();   // all stores drained before publish
      if (tid == 0)
        __hip_atomic_store(f1 + ((size_t)(t - 1) * 64 + ub) * FSTR, 1,
                           __ATOMIC_RELAXED, __HIP_MEMORY_SCOPE_AGENT);
    }
  }
}

// ---------------- softmax finalize ----------------
__global__ void k_rowfin(const float* __restrict__ pmax, const float* __restrict__ psum,
                         const float* __restrict__ Cl, const int* __restrict__ targets,
                         float* __restrict__ loss) {
  int row = blockIdx.x;
  int tid = threadIdx.x, lane = tid & 63, w = tid >> 6;
  float mx = -1e30f, s = 0.f;
  if (tid < NCH) { mx = pmax[(size_t)row * NCH + tid]; s = psum[(size_t)row * NCH + tid]; }
#pragma unroll
  for (int d = 1; d < 64; d <<= 1) {
    float mo = __shfl_xor(mx, d, 64);
    float so = __shfl_xor(s, d, 64);
    float M2 = fmaxf(mx, mo);
    s = s * __expf(mx - M2) + so * __expf(mo - M2);
    mx = M2;
  }
  __shared__ float2 wred[4];
  if (lane == 0) wred[w] = make_float2(mx, s);
  __syncthreads();
  if (tid == 0) {
    float M = wred[0].x, S = wred[0].y;
#pragma unroll
    for (int i = 1; i < 4; ++i) {
      float M2 = fmaxf(M, wred[i].x);
      S = S * __expf(M - M2) + wred[i].y * __expf(wred[i].x - M2);
      M = M2;
    }
    float logZ = M + logf(S);
    int tgt = targets[row];
    float xt = Cl[(size_t)row * V + tgt];
    loss[row] = logZ - xt;
  }
}

__global__ void k_cost(const float* __restrict__ loss, float* __restrict__ out) {
  int tid = threadIdx.x, lane = tid & 63, w = tid >> 6;
  float s = 0.f;
  for (int i = tid; i < BT; i += 256) s += loss[i];
#pragma unroll
  for (int d = 1; d < 64; d <<= 1) s += __shfl_xor(s, d, 64);
  __shared__ float ws4[4];
  if (lane == 0) ws4[w] = s;
  __syncthreads();
  if (tid == 0) out[0] = (ws4[0] + ws4[1] + ws4[2] + ws4[3]) * (1.0f / B);
}

// ---------------- host ----------------
extern "C" void kernel_launch(void* const* d_in, const int* in_sizes, int n_in,
                              void* d_out, int out_size, void* d_ws, size_t ws_size,
                              hipStream_t stream) {
  const int*   input_data = (const int*)d_in[0];
  const int*   targets    = (const int*)d_in[1];
  const float* emb        = (const float*)d_in[2];
  const float* softmax_b  = (const float*)d_in[3];
  const float* W0         = (const float*)d_in[4];
  const float* b0         = (const float*)d_in[5];
  const float* W1         = (const float*)d_in[6];
  const float* b1         = (const float*)d_in[7];
  float* out = (float*)d_out;
  char*  ws  = (char*)d_ws;

  u16*   W0T  = (u16*)(ws + OFF_W0T);
  u16*   W1T  = (u16*)(ws + OFF_W1T);
  u16*   Ebf  = (u16*)(ws + OFF_EBF);
  u16*   Xbf  = (u16*)(ws + OFF_XBF);
  u16*   xp0p = (u16*)(ws + OFF_XP0);
  u16*   H1bf = (u16*)(ws + OFF_H1);
  u16*   hseq = (u16*)(ws + OFF_HSEQ);
  int*   sync = (int*)(ws + OFF_SYNC);
  float* pmax = (float*)(ws + OFF_PMAX);
  float* psum = (float*)(ws + OFF_PSUM);
  float* lossb= (float*)(ws + OFF_LOSS);

  // prep: weight transposes (bf16), embedding convert, X gather, R[0..1]+flags zero
  k_transpose_cvt<<<dim3(G / 32, 2048 / 32), 256, 0, stream>>>(W0, W0T, 2048, G);
  k_transpose_cvt<<<dim3(G / 32, 2048 / 32), 256, 0, stream>>>(W1, W1T, 2048, G);
  k_cvt_bf16<<<2048, 256, 0, stream>>>(emb, Ebf, V * H / 4);
  k_gather_x<<<BT, 256, 0, stream>>>(emb, input_data, Xbf);
  k_zero<<<64, 256, 0, stream>>>((unsigned int*)(ws + OFF_HSEQ), RSTRIDE);  // R[0],R[1]
  k_zero<<<256, 256, 0, stream>>>((unsigned int*)(ws + OFF_SYNC), (int)(SZ_SYNC / 4));

  // xp0p = X @ W0[0:1024,:] + b0  (bf16, [t][ub][wv][col][b] layout)
  k_gemm<1><<<dim3(G / 128, BT / 128), 256, 0, stream>>>(
      Xbf, H, W0T, 2048, (float*)xp0p, G, b0, H);

  // persistent LSTM v2: wave-local gates, flag-sync decoupled chains
  k_lstm2<<<dim3(NWG3), dim3(512), 0, stream>>>(
      W0T, W1T, xp0p, b1, hseq, H1bf, sync);

  // logits = H1 @ E^T + softmax_b, 256^2 3-ring counted-vmcnt GEMM + partials
  k_gemm256<true><<<dim3(V / 256, BT / 256), 512, 0, stream>>>(
      H1bf, H, Ebf, H, out, V, softmax_b, pmax, psum, NCH);

  // per-row logZ + NLL, then cost = sum/B appended after logits
  k_rowfin<<<BT, 256, 0, stream>>>(pmax, psum, out, targets, lossb);
  k_cost<<<1, 256, 0, stream>>>(lossb, out + (size_t)BT * V);
}

// Round 10
// 2993.324 us; speedup vs baseline: 1.7697x; 1.7697x over previous
//
#include <hip/hip_runtime.h>
#include <hip/hip_bf16.h>

#define DEV static __device__ __forceinline__

typedef unsigned short u16;
typedef unsigned long long u64;
typedef __attribute__((ext_vector_type(8))) short short8;   // 8 bf16 (4 VGPRs) MFMA frag
typedef __attribute__((ext_vector_type(4))) float f32x4;    // MFMA accumulator

constexpr int V = 32000, H = 1024, B = 32, T = 256;
constexpr int BT = B * T;       // 8192 rows
constexpr int G  = 4 * H;       // 4096 gates
constexpr int NCH = V / 256;    // 125 col-chunks for softmax partials
constexpr int NWG2 = 256;       // persistent LSTM blocks (128 L0 + 128 L1), 1/CU
constexpr int RST2 = 16 * 2048 + 1024;  // u16 per chain-h-buffer (66KB incl 2KB pad)

// ---------------- workspace layout (bytes) ----------------
constexpr size_t SZ_WT    = (size_t)G * 2048 * 2;            // [4096][2048] bf16
constexpr size_t OFF_W0T  = 0;
constexpr size_t OFF_W1T  = OFF_W0T + SZ_WT;
constexpr size_t OFF_EBF  = OFF_W1T + SZ_WT;                 // [32000][1024] bf16
constexpr size_t OFF_XBF  = OFF_EBF + (size_t)V * H * 2;     // [8192][1024] bf16 (row = t*32+b)
constexpr size_t OFF_XP0  = OFF_XBF + (size_t)BT * H * 2;    // bf16 perm [t][wgu][b][q*8+uu]
constexpr size_t OFF_H1   = OFF_XP0 + (size_t)BT * G * 2;    // [8192][1024] bf16 (row = b*256+t)
constexpr size_t OFF_HSEQ = OFF_H1 + (size_t)BT * H * 2;     // R[chain][0..T+1], write-once
constexpr size_t SZ_HSEQ  = (size_t)2 * (T + 2) * RST2 * 2;
constexpr size_t OFF_SYNC = OFF_HSEQ + SZ_HSEQ;              // f0[2][256][128], f1[2][256][128]
constexpr size_t SZ_SYNC  = (size_t)2 * 2 * 256 * 128 * 4;   // 512KB
constexpr size_t OFF_PMAX = OFF_SYNC + SZ_SYNC;              // [8192][125] f32
constexpr size_t OFF_PSUM = OFF_PMAX + (size_t)BT * NCH * 4;
constexpr size_t OFF_LOSS = OFF_PSUM + (size_t)BT * NCH * 4; // [8192] f32

DEV u16 f2bf(float x) {  // RNE f32 -> bf16 bits
  union { float f; unsigned int u; } v; v.f = x;
  unsigned int r = v.u + 0x7fffu + ((v.u >> 16) & 1u);
  return (u16)(r >> 16);
}
DEV float bf2f(u16 b) {
  union { unsigned int u; float f; } v; v.u = ((unsigned int)b) << 16;
  return v.f;
}
DEV float sigm(float x) { return 1.f / (1.f + expf(-x)); }

DEV void gload_lds16(const u16* g, u16* l) {
  __builtin_amdgcn_global_load_lds(
      (__attribute__((address_space(1))) void*)g,
      (__attribute__((address_space(3))) void*)l, 16, 0, 0);
}

// ---------------- prep kernels ----------------

__global__ void k_transpose_cvt(const float* __restrict__ in, u16* __restrict__ out,
                                int R, int C) {
  __shared__ float tile[32][33];
  int bc = blockIdx.x * 32, br = blockIdx.y * 32;
  int tx = threadIdx.x & 31, ty0 = threadIdx.x >> 5;
#pragma unroll
  for (int i = 0; i < 4; ++i) {
    int ty = ty0 + i * 8;
    tile[ty][tx] = in[(size_t)(br + ty) * C + bc + tx];
  }
  __syncthreads();
#pragma unroll
  for (int i = 0; i < 4; ++i) {
    int ty = ty0 + i * 8;
    out[(size_t)(bc + ty) * R + br + tx] = f2bf(tile[tx][ty]);
  }
}

__global__ void k_cvt_bf16(const float* __restrict__ in, u16* __restrict__ out, int n4) {
  int i = blockIdx.x * blockDim.x + threadIdx.x;
  int stride = gridDim.x * blockDim.x;
  for (; i < n4; i += stride) {
    float4 v = ((const float4*)in)[i];
    ushort4 o;
    o.x = f2bf(v.x); o.y = f2bf(v.y); o.z = f2bf(v.z); o.w = f2bf(v.w);
    ((ushort4*)out)[i] = o;
  }
}

__global__ void k_gather_x(const float* __restrict__ emb, const int* __restrict__ inp,
                           u16* __restrict__ Xbf) {
  int row = blockIdx.x;
  int t = row >> 5, b = row & 31;
  int tok = inp[b * T + t];
  const float4* src = (const float4*)(emb + (size_t)tok * H);
  ushort4* dst = (ushort4*)(Xbf + (size_t)row * H);
  float4 v = src[threadIdx.x];
  ushort4 o;
  o.x = f2bf(v.x); o.y = f2bf(v.y); o.z = f2bf(v.z); o.w = f2bf(v.w);
  dst[threadIdx.x] = o;
}

__global__ void k_zero(unsigned int* __restrict__ p, int nwords) {
  int i = blockIdx.x * blockDim.x + threadIdx.x;
  int stride = gridDim.x * blockDim.x;
  for (; i < nwords; i += stride) p[i] = 0u;
}

// ---------------- 128x128 bf16 MFMA GEMM (m97 structure, for xp0) --------
// CMODE 1: C bf16, permuted [t][wgu(128)][b(32)][q*8+uu(32)].
template <int CMODE>
__global__ __launch_bounds__(256)
void k_gemm(const u16* __restrict__ A, int lda,
            const u16* __restrict__ Bt, int ldb,
            float* __restrict__ C, int ldc,
            const float* __restrict__ bias, int K) {
  __shared__ alignas(16) u16 ldsA[128 * 32];
  __shared__ alignas(16) u16 ldsB[128 * 32];

  unsigned nwg = gridDim.x * gridDim.y;
  unsigned flat = blockIdx.y * gridDim.x + blockIdx.x;
  unsigned nf = (flat & 7) * (nwg >> 3) + (flat >> 3);
  unsigned bx = nf % gridDim.x, by = nf / gridDim.x;

  int tid = threadIdx.x, lane = tid & 63, w = tid >> 6;
  int row0 = by * 128, col0 = bx * 128;
  int wr = w >> 1, wc = w & 1;
  int c15 = lane & 15, q4 = lane >> 4;

  const u16* ag[2]; const u16* bg[2];
#pragma unroll
  for (int j = 0; j < 2; ++j) {
    int r = (j * 4 + w) * 16 + (lane >> 2);
    int k = (lane & 3) * 8;
    ag[j] = A + (size_t)(row0 + r) * lda + k;
    bg[j] = Bt + (size_t)(col0 + r) * ldb + k;
  }
  u16* lA0 = ldsA + (size_t)(0 + w) * 512;
  u16* lA1 = ldsA + (size_t)(4 + w) * 512;
  u16* lB0 = ldsB + (size_t)(0 + w) * 512;
  u16* lB1 = ldsB + (size_t)(4 + w) * 512;

  f32x4 acc[4][4];
#pragma unroll
  for (int m = 0; m < 4; ++m)
#pragma unroll
    for (int n = 0; n < 4; ++n) acc[m][n] = (f32x4){0.f, 0.f, 0.f, 0.f};

  int nk = K >> 5;
  for (int kk = 0; kk < nk; ++kk) {
    int kb = kk * 32;
    gload_lds16(ag[0] + kb, lA0);
    gload_lds16(ag[1] + kb, lA1);
    gload_lds16(bg[0] + kb, lB0);
    gload_lds16(bg[1] + kb, lB1);
    __syncthreads();

    short8 af[4], bfr[4];
#pragma unroll
    for (int m = 0; m < 4; ++m)
      af[m] = *(const short8*)(ldsA + (wr * 64 + m * 16 + c15) * 32 + q4 * 8);
#pragma unroll
    for (int n = 0; n < 4; ++n)
      bfr[n] = *(const short8*)(ldsB + (wc * 64 + n * 16 + c15) * 32 + q4 * 8);
#pragma unroll
    for (int m = 0; m < 4; ++m)
#pragma unroll
      for (int n = 0; n < 4; ++n)
        acc[m][n] = __builtin_amdgcn_mfma_f32_16x16x32_bf16(af[m], bfr[n], acc[m][n], 0, 0, 0);
    __syncthreads();
  }

  float bias_n[4];
#pragma unroll
  for (int n = 0; n < 4; ++n) bias_n[n] = bias[col0 + wc * 64 + n * 16 + c15];

#pragma unroll
  for (int m = 0; m < 4; ++m) {
#pragma unroll
    for (int jr = 0; jr < 4; ++jr) {
      int r_g = row0 + wr * 64 + m * 16 + q4 * 4 + jr;
#pragma unroll
      for (int n = 0; n < 4; ++n) {
        int c_g = col0 + wc * 64 + n * 16 + c15;
        float val = acc[m][n][jr] + bias_n[n];
        if (CMODE == 0) {
          C[(size_t)r_g * ldc + c_g] = val;
        } else {
          int tt = r_g >> 5, bb = r_g & 31;
          int q = c_g >> 10, wgup = (c_g & 1023) >> 3, uu = c_g & 7;
          ((u16*)C)[((((size_t)tt * 128 + wgup) * 32 + bb) * 32) + q * 8 + uu] = f2bf(val);
        }
      }
    }
  }
}

// ---------------- 256x256 8-wave counted-vmcnt GEMM (logits) --------------
// 3-deep LDS ring (96KB): staging tile t+2 never touches a buffer being read.
// vmcnt(4) at tile end; XOR unit-swizzle on both stage-source and frag-read.
constexpr int GNT = 32;  // K-tiles (K=1024)

DEV void stage256(const u16* __restrict__ A, int lda,
                  const u16* __restrict__ Bt, int ldb,
                  int row0, int col0, u16* lds, int t, int h, int tid) {
  int op = h >> 1, hh = h & 1;
  int wid = tid >> 6, lane = tid & 63;
  int r = hh * 128 + wid * 16 + (lane >> 2);
  int k = t * 32 + (((lane & 3) ^ ((lane >> 2) & 3)) << 3);  // XOR unit-swizzle
  const u16* g = (op == 0) ? (A + (size_t)(row0 + r) * lda + k)
                           : (Bt + (size_t)(col0 + r) * ldb + k);
  u16* l = lds + (size_t)((op * 3 + (t % 3)) * 8192 + (hh * 128 + wid * 16) * 32);
  gload_lds16(g, l);
}

template <bool SM_EPI>
__global__ __launch_bounds__(512)
void k_gemm256(const u16* __restrict__ A, int lda,
               const u16* __restrict__ Bt, int ldb,
               float* __restrict__ C, int ldc,
               const float* __restrict__ bias,
               float* __restrict__ pmax, float* __restrict__ psum, int nch) {
  __shared__ alignas(16) u16 lds[6 * 8192];   // 96KB: [op(2)][slot(3)][256*32]

  unsigned nwg = gridDim.x * gridDim.y;       // 4000, %8==0
  unsigned flat = blockIdx.y * gridDim.x + blockIdx.x;
  unsigned nf = (flat & 7) * (nwg >> 3) + (flat >> 3);
  int bx = nf % gridDim.x, by = nf / gridDim.x;
  int row0 = by * 256, col0 = bx * 256;

  int tid = threadIdx.x, lane = tid & 63, wid = tid >> 6;
  int wr = wid >> 2, wc = wid & 3;            // 2M x 4N waves
  int c15 = lane & 15, q4 = lane >> 4;
  int usw = (q4 ^ (c15 & 3)) << 3;            // swizzled unit offset

  f32x4 acc[8][4];
#pragma unroll
  for (int m = 0; m < 8; ++m)
#pragma unroll
    for (int n = 0; n < 4; ++n) acc[m][n] = (f32x4){0.f, 0.f, 0.f, 0.f};

  // prologue: stage tiles 0 and 1
#pragma unroll
  for (int h = 0; h < 4; ++h) stage256(A, lda, Bt, ldb, row0, col0, lds, 0, h, tid);
#pragma unroll
  for (int h = 0; h < 4; ++h) stage256(A, lda, Bt, ldb, row0, col0, lds, 1, h, tid);
  asm volatile("s_waitcnt vmcnt(4)" ::: "memory");   // tile 0 staged
  __builtin_amdgcn_sched_barrier(0);
  __builtin_amdgcn_s_barrier();

  short8 af[4], bfr[4];

  for (int t = 0; t < GNT; ++t) {
    const u16* la = lds + (size_t)(t % 3) * 8192;
    const u16* lb = lds + (size_t)(3 + t % 3) * 8192;

    // ---- phase 0: m 0..3 ----
#pragma unroll
    for (int m = 0; m < 4; ++m)
      af[m] = *(const short8*)(la + (wr * 128 + m * 16 + c15) * 32 + usw);
#pragma unroll
    for (int n = 0; n < 4; ++n)
      bfr[n] = *(const short8*)(lb + (wc * 64 + n * 16 + c15) * 32 + usw);
    if (t + 2 < GNT) {
      stage256(A, lda, Bt, ldb, row0, col0, lds, t + 2, 0, tid);
      stage256(A, lda, Bt, ldb, row0, col0, lds, t + 2, 1, tid);
    }
    __builtin_amdgcn_s_barrier();
    asm volatile("s_waitcnt lgkmcnt(0)" ::: "memory");
    __builtin_amdgcn_sched_barrier(0);
    __builtin_amdgcn_s_setprio(1);
#pragma unroll
    for (int m = 0; m < 4; ++m)
#pragma unroll
      for (int n = 0; n < 4; ++n)
        acc[m][n] = __builtin_amdgcn_mfma_f32_16x16x32_bf16(af[m], bfr[n], acc[m][n], 0, 0, 0);
    __builtin_amdgcn_s_setprio(0);
    __builtin_amdgcn_s_barrier();

    // ---- phase 1: m 4..7 ----
#pragma unroll
    for (int m = 0; m < 4; ++m)
      af[m] = *(const short8*)(la + (wr * 128 + (m + 4) * 16 + c15) * 32 + usw);
    if (t + 2 < GNT) {
      stage256(A, lda, Bt, ldb, row0, col0, lds, t + 2, 2, tid);
      stage256(A, lda, Bt, ldb, row0, col0, lds, t + 2, 3, tid);
    }
    __builtin_amdgcn_s_barrier();
    asm volatile("s_waitcnt lgkmcnt(0)" ::: "memory");
    __builtin_amdgcn_sched_barrier(0);
    __builtin_amdgcn_s_setprio(1);
#pragma unroll
    for (int m = 0; m < 4; ++m)
#pragma unroll
      for (int n = 0; n < 4; ++n)
        acc[m + 4][n] = __builtin_amdgcn_mfma_f32_16x16x32_bf16(af[m], bfr[n], acc[m + 4][n], 0, 0, 0);
    __builtin_amdgcn_s_setprio(0);
    if (t < GNT - 2) {
      asm volatile("s_waitcnt vmcnt(4)" ::: "memory");
      __builtin_amdgcn_sched_barrier(0);
    } else if (t == GNT - 2) {
      asm volatile("s_waitcnt vmcnt(0)" ::: "memory");
      __builtin_amdgcn_sched_barrier(0);
    }
    __builtin_amdgcn_s_barrier();
  }

  // ---- epilogue: bias + C write + online-softmax partials ----
  float bias_n[4];
#pragma unroll
  for (int n = 0; n < 4; ++n) bias_n[n] = bias[col0 + wc * 64 + n * 16 + c15];

  float2* red = (float2*)lds;   // overlay [256][4]
  __syncthreads();

#pragma unroll
  for (int m = 0; m < 8; ++m) {
#pragma unroll
    for (int jr = 0; jr < 4; ++jr) {
      int rloc = wr * 128 + m * 16 + q4 * 4 + jr;
      int r_g = row0 + rloc;
      float v[4];
#pragma unroll
      for (int n = 0; n < 4; ++n) {
        int c_g = col0 + wc * 64 + n * 16 + c15;
        float val = acc[m][n][jr] + bias_n[n];
        C[(size_t)r_g * ldc + c_g] = val;
        v[n] = val;
      }
      if (SM_EPI) {
        float mx = fmaxf(fmaxf(v[0], v[1]), fmaxf(v[2], v[3]));
        float s = __expf(v[0] - mx) + __expf(v[1] - mx) + __expf(v[2] - mx) + __expf(v[3] - mx);
#pragma unroll
        for (int d = 1; d < 16; d <<= 1) {
          float mo = __shfl_xor(mx, d, 64);
          float so = __shfl_xor(s, d, 64);
          float M2 = fmaxf(mx, mo);
          s = s * __expf(mx - M2) + so * __expf(mo - M2);
          mx = M2;
        }
        if (c15 == 0) red[rloc * 4 + wc] = make_float2(mx, s);
      }
    }
  }
  if (SM_EPI) {
    __syncthreads();
    if (tid < 256) {
      float M = -1e30f, S = 0.f;
#pragma unroll
      for (int i = 0; i < 4; ++i) {
        float2 a = red[tid * 4 + i];
        float M2 = fmaxf(M, a.x);
        S = S * __expf(M - M2) + a.y * __expf(a.x - M2);
        M = M2;
      }
      pmax[(size_t)(row0 + tid) * nch + bx] = M;
      psum[(size_t)(row0 + tid) * nch + bx] = S;
    }
  }
}

// ---------------- persistent LSTM v3: r8 structure + 2 batch-chains -------
// Batch rows are independent recurrences: split into 2 chains of 16 rows,
// processed alternately by the same blocks with the same in-VGPR weights.
// Chain A's flag-propagation latency is covered by chain B's processing.
// All r8 idioms kept: single-wave packed-flag polling, all-loads-up-front,
// LDS cross-wave K-reduce, publish = syncthreads (vmcnt drain) + 1 store.

#define RED3(w_, nt_, r_, c_) red[(((w_)*2 + (nt_)) * 16 + (r_)) * 16 + (c_)]

DEV void wait_flags(const int* __restrict__ fa, const int* __restrict__ fb) {
  if (threadIdx.x < 64) {
    int lane = threadIdx.x;
    while (true) {
      int ok = 1;
      if (fa) {
        int a0 = __hip_atomic_load(fa + lane,      __ATOMIC_RELAXED, __HIP_MEMORY_SCOPE_AGENT);
        int a1 = __hip_atomic_load(fa + 64 + lane, __ATOMIC_RELAXED, __HIP_MEMORY_SCOPE_AGENT);
        ok &= (a0 != 0) & (a1 != 0);
      }
      if (fb) {
        int b0 = __hip_atomic_load(fb + lane,      __ATOMIC_RELAXED, __HIP_MEMORY_SCOPE_AGENT);
        int b1 = __hip_atomic_load(fb + 64 + lane, __ATOMIC_RELAXED, __HIP_MEMORY_SCOPE_AGENT);
        ok &= (b0 != 0) & (b1 != 0);
      }
      if (__all(ok)) break;
      __builtin_amdgcn_s_sleep(1);
    }
  }
  __builtin_amdgcn_sched_barrier(0);
  __syncthreads();
}

template <int KH, bool IS_L0>
DEV void lstm_role(const u16* __restrict__ WT,      // [4096][2048] bf16
                   const u16* __restrict__ xp0p,    // bf16 perm (L0) or null
                   const float* __restrict__ zb1,   // b1 (L1) or null
                   u16* __restrict__ hseq, u16* __restrict__ H1bf,
                   int* __restrict__ f0, int* __restrict__ f1,
                   float* __restrict__ red, int wgu) {
  constexpr int KOFF = IS_L0 ? 1024 : 0;   // weight-k offset (h-part of W0)
  constexpr int KS = KH / 4;               // per-wave K slice
  constexpr int NKC = KS / 32;             // k-chunks per wave (8 or 16)
  int tid = threadIdx.x, lane = tid & 63, w = tid >> 6;
  int c15 = lane & 15, q4 = lane >> 4;
  int eb = (tid >> 3) & 15, eu = tid & 7;  // epilogue identity; tid<128 active
  bool epi = tid < 128;

  // ---- preload weight slice into registers (once) ----
  short8 wfr[2][NKC];
#pragma unroll
  for (int nt = 0; nt < 2; ++nt) {
    int lr = nt * 16 + c15;                // local row = gate*8 + unit
    const u16* rp = WT + (size_t)((lr >> 3) * 1024 + wgu * 8 + (lr & 7)) * 2048
                    + KOFF + w * KS + q4 * 8;
#pragma unroll
    for (int kc = 0; kc < NKC; ++kc)
      wfr[nt][kc] = *(const short8*)(rp + kc * 32);
  }

  float zpc[4];
  if (!IS_L0) {
#pragma unroll
    for (int q = 0; q < 4; ++q) zpc[q] = zb1[q * 1024 + wgu * 8 + eu];
  }
  float cregs[2] = {0.f, 0.f};             // c-state per chain (static index)

  for (int it_t = 0; it_t < T; ++it_t) {
    int t = IS_L0 ? it_t : it_t + 1;       // L0 computes h0(t); L1 computes h1(t-1)
#pragma unroll
    for (int c = 0; c < 2; ++c) {
      float zp[4];
      if (IS_L0) {
        int b = c * 16 + eb;               // prefetch BEFORE flag wait
#pragma unroll
        for (int q = 0; q < 4; ++q)
          zp[q] = bf2f(xp0p[((((size_t)t * 128 + wgu) * 32 + b) * 32) + q * 8 + eu]);
      } else {
#pragma unroll
        for (int q = 0; q < 4; ++q) zp[q] = zpc[q];
      }

      if (IS_L0) {
        if (t >= 1) wait_flags(f0 + ((size_t)c * 256 + (t - 1)) * 128, nullptr);
      } else {
        wait_flags(f0 + ((size_t)c * 256 + (t - 1)) * 128,
                   t >= 2 ? f1 + ((size_t)c * 256 + (t - 2)) * 128 : nullptr);
      }

      const u16* hread = hseq + ((size_t)c * (T + 2) + t) * RST2;
      short8 afr[NKC];
#pragma unroll
      for (int kc = 0; kc < NKC; ++kc)     // ALL loads up front: one latency
        afr[kc] = *(const short8*)(hread + (size_t)c15 * 2048 + w * KS + kc * 32 + q4 * 8);

      f32x4 acc0 = (f32x4){0.f, 0.f, 0.f, 0.f};
      f32x4 acc1 = (f32x4){0.f, 0.f, 0.f, 0.f};
#pragma unroll
      for (int kc = 0; kc < NKC; ++kc) {
        acc0 = __builtin_amdgcn_mfma_f32_16x16x32_bf16(afr[kc], wfr[0][kc], acc0, 0, 0, 0);
        acc1 = __builtin_amdgcn_mfma_f32_16x16x32_bf16(afr[kc], wfr[1][kc], acc1, 0, 0, 0);
      }

      // cross-wave K reduction via LDS
#pragma unroll
      for (int jr = 0; jr < 4; ++jr) {
        RED3(w, 0, q4 * 4 + jr, c15) = acc0[jr];
        RED3(w, 1, q4 * 4 + jr, c15) = acc1[jr];
      }
      __syncthreads();

      if (epi) {
        float z[4];
#pragma unroll
        for (int q = 0; q < 4; ++q) {
          int lr = q * 8 + eu, nt = lr >> 4, cc = lr & 15;
          z[q] = RED3(0, nt, eb, cc) + RED3(1, nt, eb, cc) +
                 RED3(2, nt, eb, cc) + RED3(3, nt, eb, cc) + zp[q];
        }
        float gi = sigm(z[0]);
        float gj = tanhf(z[1]);
        float gf = sigm(z[2] + 1.f);       // forget_bias = 1.0
        float go = sigm(z[3]);
        cregs[c] = cregs[c] * gf + gi * gj;
        float hv = go * tanhf(cregs[c]);

        int hb = (int)f2bf(hv);
        int hp = __shfl_xor(hb, 1, 64);    // partner unit (eu^1), same eb
        if (!(tid & 1)) {
          unsigned int pack = (unsigned int)(u16)hb | ((unsigned int)(u16)hp << 16);
          u16* hwr = hseq + ((size_t)c * (T + 2) + t + 1) * RST2 + (IS_L0 ? 0 : 1024);
          __hip_atomic_store((unsigned int*)(hwr + (size_t)eb * 2048 + wgu * 8 + eu), pack,
                             __ATOMIC_RELAXED, __HIP_MEMORY_SCOPE_AGENT);
          if (!IS_L0) {
            int b = c * 16 + eb;
            __builtin_nontemporal_store(pack,
                (unsigned int*)(H1bf + ((size_t)b * T + (t - 1)) * H + wgu * 8 + eu));
          }
        }
      }

      // publish: syncthreads (vmcnt drain) + one flag store, zero contention
      __syncthreads();
      if (tid == 0) {
        int* word = IS_L0 ? (f0 + ((size_t)c * 256 + t) * 128 + wgu)
                          : (f1 + ((size_t)c * 256 + (t - 1)) * 128 + wgu);
        __hip_atomic_store(word, 1, __ATOMIC_RELAXED, __HIP_MEMORY_SCOPE_AGENT);
      }
    }
  }
}

__global__ __launch_bounds__(256, 1)
void k_lstm3(const u16* __restrict__ W0T, const u16* __restrict__ W1T,
             const u16* __restrict__ xp0p, const float* __restrict__ b1,
             u16* __restrict__ hseq, u16* __restrict__ H1bf,
             int* __restrict__ sync) {
  __shared__ float red[4 * 2 * 16 * 16];   // 8KB
  int* f0 = sync;                          // [2][256][128]
  int* f1 = sync + 2 * 256 * 128;
  int wg = blockIdx.x;
  if (wg < 128)
    lstm_role<1024, true>(W0T, xp0p, nullptr, hseq, H1bf, f0, f1, red, wg);
  else
    lstm_role<2048, false>(W1T, nullptr, b1, hseq, H1bf, f0, f1, red, wg - 128);
}

// ---------------- softmax finalize ----------------
__global__ void k_rowfin(const float* __restrict__ pmax, const float* __restrict__ psum,
                         const float* __restrict__ Cl, const int* __restrict__ targets,
                         float* __restrict__ loss) {
  int row = blockIdx.x;
  int tid = threadIdx.x, lane = tid & 63, w = tid >> 6;
  float mx = -1e30f, s = 0.f;
  if (tid < NCH) { mx = pmax[(size_t)row * NCH + tid]; s = psum[(size_t)row * NCH + tid]; }
#pragma unroll
  for (int d = 1; d < 64; d <<= 1) {
    float mo = __shfl_xor(mx, d, 64);
    float so = __shfl_xor(s, d, 64);
    float M2 = fmaxf(mx, mo);
    s = s * __expf(mx - M2) + so * __expf(mo - M2);
    mx = M2;
  }
  __shared__ float2 wred[4];
  if (lane == 0) wred[w] = make_float2(mx, s);
  __syncthreads();
  if (tid == 0) {
    float M = wred[0].x, S = wred[0].y;
#pragma unroll
    for (int i = 1; i < 4; ++i) {
      float M2 = fmaxf(M, wred[i].x);
      S = S * __expf(M - M2) + wred[i].y * __expf(wred[i].x - M2);
      M = M2;
    }
    float logZ = M + logf(S);
    int tgt = targets[row];
    float xt = Cl[(size_t)row * V + tgt];
    loss[row] = logZ - xt;
  }
}

__global__ void k_cost(const float* __restrict__ loss, float* __restrict__ out) {
  int tid = threadIdx.x, lane = tid & 63, w = tid >> 6;
  float s = 0.f;
  for (int i = tid; i < BT; i += 256) s += loss[i];
#pragma unroll
  for (int d = 1; d < 64; d <<= 1) s += __shfl_xor(s, d, 64);
  __shared__ float ws4[4];
  if (lane == 0) ws4[w] = s;
  __syncthreads();
  if (tid == 0) out[0] = (ws4[0] + ws4[1] + ws4[2] + ws4[3]) * (1.0f / B);
}

// ---------------- host ----------------
extern "C" void kernel_launch(void* const* d_in, const int* in_sizes, int n_in,
                              void* d_out, int out_size, void* d_ws, size_t ws_size,
                              hipStream_t stream) {
  const int*   input_data = (const int*)d_in[0];
  const int*   targets    = (const int*)d_in[1];
  const float* emb        = (const float*)d_in[2];
  const float* softmax_b  = (const float*)d_in[3];
  const float* W0         = (const float*)d_in[4];
  const float* b0         = (const float*)d_in[5];
  const float* W1         = (const float*)d_in[6];
  const float* b1         = (const float*)d_in[7];
  float* out = (float*)d_out;
  char*  ws  = (char*)d_ws;

  u16*   W0T  = (u16*)(ws + OFF_W0T);
  u16*   W1T  = (u16*)(ws + OFF_W1T);
  u16*   Ebf  = (u16*)(ws + OFF_EBF);
  u16*   Xbf  = (u16*)(ws + OFF_XBF);
  u16*   xp0p = (u16*)(ws + OFF_XP0);
  u16*   H1bf = (u16*)(ws + OFF_H1);
  u16*   hseq = (u16*)(ws + OFF_HSEQ);
  int*   sync = (int*)(ws + OFF_SYNC);
  float* pmax = (float*)(ws + OFF_PMAX);
  float* psum = (float*)(ws + OFF_PSUM);
  float* lossb= (float*)(ws + OFF_LOSS);

  // prep: weight transposes (bf16), embedding convert, X gather, R/flags zero
  k_transpose_cvt<<<dim3(G / 32, 2048 / 32), 256, 0, stream>>>(W0, W0T, 2048, G);
  k_transpose_cvt<<<dim3(G / 32, 2048 / 32), 256, 0, stream>>>(W1, W1T, 2048, G);
  k_cvt_bf16<<<2048, 256, 0, stream>>>(emb, Ebf, V * H / 4);
  k_gather_x<<<BT, 256, 0, stream>>>(emb, input_data, Xbf);
  // zero R[c][0..1] for both chains + all flags
  k_zero<<<32, 256, 0, stream>>>((unsigned int*)(ws + OFF_HSEQ), RST2);
  k_zero<<<32, 256, 0, stream>>>(
      (unsigned int*)(ws + OFF_HSEQ + (size_t)(T + 2) * RST2 * 2), RST2);
  k_zero<<<64, 256, 0, stream>>>((unsigned int*)(ws + OFF_SYNC), (int)(SZ_SYNC / 4));

  // xp0p = X @ W0[0:1024,:] + b0  (bf16, block-permuted layout)
  k_gemm<1><<<dim3(G / 128, BT / 128), 256, 0, stream>>>(
      Xbf, H, W0T, 2048, (float*)xp0p, G, b0, H);

  // persistent LSTM v3: 2 batch-chains, flag-sync, weights in VGPRs
  k_lstm3<<<dim3(NWG2), dim3(256), 0, stream>>>(
      W0T, W1T, xp0p, b1, hseq, H1bf, sync);

  // logits = H1 @ E^T + softmax_b, 256^2 3-ring counted-vmcnt GEMM + partials
  k_gemm256<true><<<dim3(V / 256, BT / 256), 512, 0, stream>>>(
      H1bf, H, Ebf, H, out, V, softmax_b, pmax, psum, NCH);

  // per-row logZ + NLL, then cost = sum/B appended after logits
  k_rowfin<<<BT, 256, 0, stream>>>(pmax, psum, out, targets, lossb);
  k_cost<<<1, 256, 0, stream>>>(lossb, out + (size_t)BT * V);
}

// Round 11
// 2852.290 us; speedup vs baseline: 1.8572x; 1.0494x over previous
//
#include <hip/hip_runtime.h>
#include <hip/hip_bf16.h>

#define DEV static __device__ __forceinline__

typedef unsigned short u16;
typedef unsigned long long u64;
typedef __attribute__((ext_vector_type(8))) short short8;   // 8 bf16 (4 VGPRs) MFMA frag
typedef __attribute__((ext_vector_type(4))) float f32x4;    // MFMA accumulator

constexpr int V = 32000, H = 1024, B = 32, T = 256;
constexpr int BT = B * T;       // 8192 rows
constexpr int G  = 4 * H;       // 4096 gates
constexpr int NCH = V / 256;    // 125 col-chunks for softmax partials
constexpr int NWG2 = 256;       // persistent LSTM blocks (128 L0 + 128 L1), 1/CU
constexpr int RSTRIDE = 32 * 2048 + 2048;  // u16 per h-buffer (132KB incl 4KB pad)

// ---------------- workspace layout (bytes) ----------------
constexpr size_t SZ_WT    = (size_t)G * 2048 * 2;            // [4096][2048] bf16
constexpr size_t OFF_W0T  = 0;
constexpr size_t OFF_W1T  = OFF_W0T + SZ_WT;
constexpr size_t OFF_EBF  = OFF_W1T + SZ_WT;                 // [32000][1024] bf16
constexpr size_t OFF_XBF  = OFF_EBF + (size_t)V * H * 2;     // [8192][1024] bf16 (row = t*32+b)
constexpr size_t OFF_XP0  = OFF_XBF + (size_t)BT * H * 2;    // bf16 perm [t][wgu][b][q*8+uu]
constexpr size_t OFF_H1   = OFF_XP0 + (size_t)BT * G * 2;    // [8192][1024] bf16 (row = b*256+t)
constexpr size_t OFF_HSEQ = OFF_H1 + (size_t)BT * H * 2;     // R[0..T+1], write-once per tick
constexpr size_t SZ_HSEQ  = (size_t)(T + 2) * RSTRIDE * 2;
constexpr size_t OFF_SYNC = OFF_HSEQ + SZ_HSEQ;              // flags f0/f1 [256][128] ints
constexpr size_t SZ_SYNC  = (size_t)2 * 256 * 128 * 4;       // 256KB
constexpr size_t OFF_PMAX = OFF_SYNC + SZ_SYNC;              // [8192][125] f32
constexpr size_t OFF_PSUM = OFF_PMAX + (size_t)BT * NCH * 4;
constexpr size_t OFF_LOSS = OFF_PSUM + (size_t)BT * NCH * 4; // [8192] f32

DEV u16 f2bf(float x) {  // RNE f32 -> bf16 bits
  union { float f; unsigned int u; } v; v.f = x;
  unsigned int r = v.u + 0x7fffu + ((v.u >> 16) & 1u);
  return (u16)(r >> 16);
}
DEV float bf2f(u16 b) {
  union { unsigned int u; float f; } v; v.u = ((unsigned int)b) << 16;
  return v.f;
}
DEV float sigm(float x) { return 1.f / (1.f + expf(-x)); }

DEV void gload_lds16(const u16* g, u16* l) {
  __builtin_amdgcn_global_load_lds(
      (__attribute__((address_space(1))) void*)g,
      (__attribute__((address_space(3))) void*)l, 16, 0, 0);
}

// ---------------- prep kernels ----------------

// batched: z=0 -> W0->W0T, z=1 -> W1->W1T  (f32 [2048][4096] -> bf16 [4096][2048])
__global__ void k_transpose_cvt2(const float* __restrict__ in0, u16* __restrict__ out0,
                                 const float* __restrict__ in1, u16* __restrict__ out1) {
  const float* in = blockIdx.z ? in1 : in0;
  u16* out = blockIdx.z ? out1 : out0;
  __shared__ float tile[32][33];
  int bc = blockIdx.x * 32, br = blockIdx.y * 32;
  int tx = threadIdx.x & 31, ty0 = threadIdx.x >> 5;
#pragma unroll
  for (int i = 0; i < 4; ++i) {
    int ty = ty0 + i * 8;
    tile[ty][tx] = in[(size_t)(br + ty) * G + bc + tx];
  }
  __syncthreads();
#pragma unroll
  for (int i = 0; i < 4; ++i) {
    int ty = ty0 + i * 8;
    out[(size_t)(bc + ty) * 2048 + br + tx] = f2bf(tile[tx][ty]);
  }
}

__global__ void k_cvt_bf16(const float* __restrict__ in, u16* __restrict__ out, int n4) {
  int i = blockIdx.x * blockDim.x + threadIdx.x;
  int stride = gridDim.x * blockDim.x;
  for (; i < n4; i += stride) {
    float4 v = ((const float4*)in)[i];
    ushort4 o;
    o.x = f2bf(v.x); o.y = f2bf(v.y); o.z = f2bf(v.z); o.w = f2bf(v.w);
    ((ushort4*)out)[i] = o;
  }
}

__global__ void k_gather_x(const float* __restrict__ emb, const int* __restrict__ inp,
                           u16* __restrict__ Xbf) {
  int row = blockIdx.x;
  int t = row >> 5, b = row & 31;
  int tok = inp[b * T + t];
  const float4* src = (const float4*)(emb + (size_t)tok * H);
  ushort4* dst = (ushort4*)(Xbf + (size_t)row * H);
  float4 v = src[threadIdx.x];
  ushort4 o;
  o.x = f2bf(v.x); o.y = f2bf(v.y); o.z = f2bf(v.z); o.w = f2bf(v.w);
  dst[threadIdx.x] = o;
}

__global__ void k_zero(unsigned int* __restrict__ p, int nwords) {
  int i = blockIdx.x * blockDim.x + threadIdx.x;
  int stride = gridDim.x * blockDim.x;
  for (; i < nwords; i += stride) p[i] = 0u;
}

// ---------------- 256x256 8-wave counted-vmcnt GEMM ----------------------
// 3-deep LDS ring (96KB): staging tile t+2 never touches a buffer being read.
// vmcnt(4) at tile end; XOR unit-swizzle on both stage-source and frag-read.
// MODE 0: C = permuted bf16 [t][wgu][b][q*8+uu] (xp0 for the LSTM), no softmax.
// MODE 1: C = f32 row-major + bias + online-softmax partials (logits).
constexpr int GNT = 32;  // K-tiles (K=1024)

DEV void stage256(const u16* __restrict__ A, int lda,
                  const u16* __restrict__ Bt, int ldb,
                  int row0, int col0, u16* lds, int t, int h, int tid) {
  int op = h >> 1, hh = h & 1;
  int wid = tid >> 6, lane = tid & 63;
  int r = hh * 128 + wid * 16 + (lane >> 2);
  int k = t * 32 + (((lane & 3) ^ ((lane >> 2) & 3)) << 3);  // XOR unit-swizzle
  const u16* g = (op == 0) ? (A + (size_t)(row0 + r) * lda + k)
                           : (Bt + (size_t)(col0 + r) * ldb + k);
  u16* l = lds + (size_t)((op * 3 + (t % 3)) * 8192 + (hh * 128 + wid * 16) * 32);
  gload_lds16(g, l);
}

template <int MODE>
__global__ __launch_bounds__(512)
void k_gemm256(const u16* __restrict__ A, int lda,
               const u16* __restrict__ Bt, int ldb,
               float* __restrict__ C, int ldc,
               const float* __restrict__ bias,
               float* __restrict__ pmax, float* __restrict__ psum, int nch) {
  __shared__ alignas(16) u16 lds[6 * 8192];   // 96KB: [op(2)][slot(3)][256*32]

  unsigned nwg = gridDim.x * gridDim.y;       // %8==0 required
  unsigned flat = blockIdx.y * gridDim.x + blockIdx.x;
  unsigned nf = (flat & 7) * (nwg >> 3) + (flat >> 3);
  int bx = nf % gridDim.x, by = nf / gridDim.x;
  int row0 = by * 256, col0 = bx * 256;

  int tid = threadIdx.x, lane = tid & 63, wid = tid >> 6;
  int wr = wid >> 2, wc = wid & 3;            // 2M x 4N waves
  int c15 = lane & 15, q4 = lane >> 4;
  int usw = (q4 ^ (c15 & 3)) << 3;            // swizzled unit offset

  f32x4 acc[8][4];
#pragma unroll
  for (int m = 0; m < 8; ++m)
#pragma unroll
    for (int n = 0; n < 4; ++n) acc[m][n] = (f32x4){0.f, 0.f, 0.f, 0.f};

  // prologue: stage tiles 0 and 1
#pragma unroll
  for (int h = 0; h < 4; ++h) stage256(A, lda, Bt, ldb, row0, col0, lds, 0, h, tid);
#pragma unroll
  for (int h = 0; h < 4; ++h) stage256(A, lda, Bt, ldb, row0, col0, lds, 1, h, tid);
  asm volatile("s_waitcnt vmcnt(4)" ::: "memory");   // tile 0 staged
  __builtin_amdgcn_sched_barrier(0);
  __builtin_amdgcn_s_barrier();

  short8 af[4], bfr[4];

  for (int t = 0; t < GNT; ++t) {
    const u16* la = lds + (size_t)(t % 3) * 8192;
    const u16* lb = lds + (size_t)(3 + t % 3) * 8192;

    // ---- phase 0: m 0..3 ----
#pragma unroll
    for (int m = 0; m < 4; ++m)
      af[m] = *(const short8*)(la + (wr * 128 + m * 16 + c15) * 32 + usw);
#pragma unroll
    for (int n = 0; n < 4; ++n)
      bfr[n] = *(const short8*)(lb + (wc * 64 + n * 16 + c15) * 32 + usw);
    if (t + 2 < GNT) {
      stage256(A, lda, Bt, ldb, row0, col0, lds, t + 2, 0, tid);
      stage256(A, lda, Bt, ldb, row0, col0, lds, t + 2, 1, tid);
    }
    __builtin_amdgcn_s_barrier();
    asm volatile("s_waitcnt lgkmcnt(0)" ::: "memory");
    __builtin_amdgcn_sched_barrier(0);
    __builtin_amdgcn_s_setprio(1);
#pragma unroll
    for (int m = 0; m < 4; ++m)
#pragma unroll
      for (int n = 0; n < 4; ++n)
        acc[m][n] = __builtin_amdgcn_mfma_f32_16x16x32_bf16(af[m], bfr[n], acc[m][n], 0, 0, 0);
    __builtin_amdgcn_s_setprio(0);
    __builtin_amdgcn_s_barrier();

    // ---- phase 1: m 4..7 ----
#pragma unroll
    for (int m = 0; m < 4; ++m)
      af[m] = *(const short8*)(la + (wr * 128 + (m + 4) * 16 + c15) * 32 + usw);
    if (t + 2 < GNT) {
      stage256(A, lda, Bt, ldb, row0, col0, lds, t + 2, 2, tid);
      stage256(A, lda, Bt, ldb, row0, col0, lds, t + 2, 3, tid);
    }
    __builtin_amdgcn_s_barrier();
    asm volatile("s_waitcnt lgkmcnt(0)" ::: "memory");
    __builtin_amdgcn_sched_barrier(0);
    __builtin_amdgcn_s_setprio(1);
#pragma unroll
    for (int m = 0; m < 4; ++m)
#pragma unroll
      for (int n = 0; n < 4; ++n)
        acc[m + 4][n] = __builtin_amdgcn_mfma_f32_16x16x32_bf16(af[m], bfr[n], acc[m + 4][n], 0, 0, 0);
    __builtin_amdgcn_s_setprio(0);
    if (t < GNT - 2) {
      asm volatile("s_waitcnt vmcnt(4)" ::: "memory");
      __builtin_amdgcn_sched_barrier(0);
    } else if (t == GNT - 2) {
      asm volatile("s_waitcnt vmcnt(0)" ::: "memory");
      __builtin_amdgcn_sched_barrier(0);
    }
    __builtin_amdgcn_s_barrier();
  }

  // ---- epilogue ----
  float bias_n[4];
#pragma unroll
  for (int n = 0; n < 4; ++n) bias_n[n] = bias[col0 + wc * 64 + n * 16 + c15];

  float2* red = (float2*)lds;   // overlay [256][4] (MODE 1 only)
  __syncthreads();

#pragma unroll
  for (int m = 0; m < 8; ++m) {
#pragma unroll
    for (int jr = 0; jr < 4; ++jr) {
      int rloc = wr * 128 + m * 16 + q4 * 4 + jr;
      int r_g = row0 + rloc;
      float v[4];
#pragma unroll
      for (int n = 0; n < 4; ++n) {
        int c_g = col0 + wc * 64 + n * 16 + c15;
        float val = acc[m][n][jr] + bias_n[n];
        if (MODE == 1) {
          C[(size_t)r_g * ldc + c_g] = val;
        } else {
          // xp0 permuted layout [t][wgu][b][q*8+uu]  (row = t*32+b)
          int tt = r_g >> 5, bb = r_g & 31;
          int q = c_g >> 10, wgup = (c_g & 1023) >> 3, uu = c_g & 7;
          ((u16*)C)[((((size_t)tt * 128 + wgup) * 32 + bb) * 32) + q * 8 + uu] = f2bf(val);
        }
        v[n] = val;
      }
      if (MODE == 1) {
        float mx = fmaxf(fmaxf(v[0], v[1]), fmaxf(v[2], v[3]));
        float s = __expf(v[0] - mx) + __expf(v[1] - mx) + __expf(v[2] - mx) + __expf(v[3] - mx);
#pragma unroll
        for (int d = 1; d < 16; d <<= 1) {
          float mo = __shfl_xor(mx, d, 64);
          float so = __shfl_xor(s, d, 64);
          float M2 = fmaxf(mx, mo);
          s = s * __expf(mx - M2) + so * __expf(mo - M2);
          mx = M2;
        }
        if (c15 == 0) red[rloc * 4 + wc] = make_float2(mx, s);
      }
    }
  }
  if (MODE == 1) {
    __syncthreads();
    if (tid < 256) {
      float M = -1e30f, S = 0.f;
#pragma unroll
      for (int i = 0; i < 4; ++i) {
        float2 a = red[tid * 4 + i];
        float M2 = fmaxf(M, a.x);
        S = S * __expf(M - M2) + a.y * __expf(a.x - M2);
        M = M2;
      }
      pmax[(size_t)(row0 + tid) * nch + bx] = M;
      psum[(size_t)(row0 + tid) * nch + bx] = S;
    }
  }
}

// ---------------- persistent LSTM: weights in VGPRs, flag-sync chains -----
// (r8 structure, verbatim: best measured 1867us. Poll loop spin w/o sleep.)

#define RED(w_, bt_, nt_, r_, c_) red[((((w_)*2 + (bt_)) * 2 + (nt_)) * 16 + (r_)) * 16 + (c_)]

DEV void wait_flags(const int* __restrict__ fa, const int* __restrict__ fb) {
  if (threadIdx.x < 64) {
    int lane = threadIdx.x;
    while (true) {
      int ok = 1;
      if (fa) {
        int a0 = __hip_atomic_load(fa + lane,      __ATOMIC_RELAXED, __HIP_MEMORY_SCOPE_AGENT);
        int a1 = __hip_atomic_load(fa + 64 + lane, __ATOMIC_RELAXED, __HIP_MEMORY_SCOPE_AGENT);
        ok &= (a0 != 0) & (a1 != 0);
      }
      if (fb) {
        int b0 = __hip_atomic_load(fb + lane,      __ATOMIC_RELAXED, __HIP_MEMORY_SCOPE_AGENT);
        int b1 = __hip_atomic_load(fb + 64 + lane, __ATOMIC_RELAXED, __HIP_MEMORY_SCOPE_AGENT);
        ok &= (b0 != 0) & (b1 != 0);
      }
      if (__all(ok)) break;
      // no s_sleep: the two dependent L3 loads self-throttle (~600cyc/iter);
      // sleep quanta only add detection latency to the serial chain.
    }
  }
  __builtin_amdgcn_sched_barrier(0);
  __syncthreads();
}

DEV void publish_flag(int* __restrict__ word) {
  __syncthreads();   // each wave's vmcnt drained -> agent h-stores at L3
  if (threadIdx.x == 0)
    __hip_atomic_store(word, 1, __ATOMIC_RELAXED, __HIP_MEMORY_SCOPE_AGENT);
}

template <int KH, bool IS_L0>
DEV void lstm_role(const u16* __restrict__ WT,      // [4096][2048] bf16
                   const u16* __restrict__ xp0p,    // bf16 perm (L0) or null
                   const float* __restrict__ zb1,   // b1 (L1) or null
                   u16* __restrict__ hseq, u16* __restrict__ H1bf,
                   int* __restrict__ f0, int* __restrict__ f1,
                   float* __restrict__ red, int wgu) {
  constexpr int KOFF = IS_L0 ? 1024 : 0;   // weight-k offset (h-part of W0)
  constexpr int KS = KH / 4;               // per-wave K slice
  constexpr int NKC = KS / 32;             // k-chunks per wave (8 or 16)
  int tid = threadIdx.x, lane = tid & 63, w = tid >> 6;
  int c15 = lane & 15, q4 = lane >> 4;
  int eb = tid >> 3, eu = tid & 7;         // epilogue identity: (b, unit)

  // ---- preload weight slice into registers (once) ----
  short8 wfr[2][NKC];
#pragma unroll
  for (int nt = 0; nt < 2; ++nt) {
    int lr = nt * 16 + c15;                // local row = gate*8 + unit
    const u16* rp = WT + (size_t)((lr >> 3) * 1024 + wgu * 8 + (lr & 7)) * 2048
                    + KOFF + w * KS + q4 * 8;
#pragma unroll
    for (int kc = 0; kc < NKC; ++kc)
      wfr[nt][kc] = *(const short8*)(rp + kc * 32);
  }

  float zpc[4];
  if (!IS_L0) {
#pragma unroll
    for (int q = 0; q < 4; ++q) zpc[q] = zb1[q * 1024 + wgu * 8 + eu];
  }
  float creg = 0.f;                        // c-state lives in a register

  for (int it_t = 0; it_t < T; ++it_t) {
    int t = IS_L0 ? it_t : it_t + 1;       // L0 computes h0(t); L1 computes h1(t-1)

    float zp[4];
    if (IS_L0) {
      // tick-private data: issue BEFORE the flag wait to hide latency
#pragma unroll
      for (int q = 0; q < 4; ++q)
        zp[q] = bf2f(xp0p[((((size_t)t * 128 + wgu) * 32 + eb) * 32) + q * 8 + eu]);
    } else {
#pragma unroll
      for (int q = 0; q < 4; ++q) zp[q] = zpc[q];
    }

    if (IS_L0) {
      if (t >= 1) wait_flags(f0 + (size_t)(t - 1) * 128, nullptr);  // h0(t-1)
    } else {
      wait_flags(f0 + (size_t)(t - 1) * 128,                        // h0(t-1)
                 t >= 2 ? f1 + (size_t)(t - 2) * 128 : nullptr);    // h1(t-2)
    }

    const u16* hread = hseq + (size_t)t * RSTRIDE;
    f32x4 acc[2][2];
#pragma unroll
    for (int bt = 0; bt < 2; ++bt)
#pragma unroll
      for (int nt = 0; nt < 2; ++nt) acc[bt][nt] = (f32x4){0.f, 0.f, 0.f, 0.f};

#pragma unroll
    for (int kc = 0; kc < NKC; ++kc) {
      int kh = w * KS + kc * 32 + q4 * 8;
      short8 a0 = *(const short8*)(hread + (size_t)c15 * 2048 + kh);
      short8 a1 = *(const short8*)(hread + (size_t)(16 + c15) * 2048 + kh);
      acc[0][0] = __builtin_amdgcn_mfma_f32_16x16x32_bf16(a0, wfr[0][kc], acc[0][0], 0, 0, 0);
      acc[0][1] = __builtin_amdgcn_mfma_f32_16x16x32_bf16(a0, wfr[1][kc], acc[0][1], 0, 0, 0);
      acc[1][0] = __builtin_amdgcn_mfma_f32_16x16x32_bf16(a1, wfr[0][kc], acc[1][0], 0, 0, 0);
      acc[1][1] = __builtin_amdgcn_mfma_f32_16x16x32_bf16(a1, wfr[1][kc], acc[1][1], 0, 0, 0);
    }

    // cross-wave K reduction via LDS
#pragma unroll
    for (int bt = 0; bt < 2; ++bt)
#pragma unroll
      for (int nt = 0; nt < 2; ++nt)
#pragma unroll
        for (int jr = 0; jr < 4; ++jr)
          RED(w, bt, nt, q4 * 4 + jr, c15) = acc[bt][nt][jr];
    __syncthreads();

    // epilogue: thread = (b=eb, unit=eu)
    int bt = eb >> 4, rr = eb & 15;
    float z[4];
#pragma unroll
    for (int q = 0; q < 4; ++q) {
      int lr = q * 8 + eu, nt = lr >> 4, cc = lr & 15;
      z[q] = RED(0, bt, nt, rr, cc) + RED(1, bt, nt, rr, cc) +
             RED(2, bt, nt, rr, cc) + RED(3, bt, nt, rr, cc) + zp[q];
    }
    float gi = sigm(z[0]);
    float gj = tanhf(z[1]);
    float gf = sigm(z[2] + 1.f);   // forget_bias = 1.0
    float go = sigm(z[3]);
    creg = creg * gf + gi * gj;
    float hv = go * tanhf(creg);

    int hb = (int)f2bf(hv);
    int hp = __shfl_xor(hb, 1, 64);  // partner unit (eu^1), same b
    if (!(tid & 1)) {
      unsigned int pack = (unsigned int)(u16)hb | ((unsigned int)(u16)hp << 16);
      u16* hwr = hseq + (size_t)(t + 1) * RSTRIDE + (IS_L0 ? 0 : 1024);
      __hip_atomic_store((unsigned int*)(hwr + (size_t)eb * 2048 + wgu * 8 + eu), pack,
                         __ATOMIC_RELAXED, __HIP_MEMORY_SCOPE_AGENT);
      if (!IS_L0)
        __builtin_nontemporal_store(pack,
            (unsigned int*)(H1bf + ((size_t)eb * T + (t - 1)) * H + wgu * 8 + eu));
    }

    // publish: syncthreads (drain) + one flag store, zero contention
    publish_flag(IS_L0 ? (f0 + (size_t)t * 128 + wgu)
                       : (f1 + (size_t)(t - 1) * 128 + wgu));
  }
}

__global__ __launch_bounds__(256, 1)
void k_lstm_persistent(const u16* __restrict__ W0T, const u16* __restrict__ W1T,
                       const u16* __restrict__ xp0p, const float* __restrict__ b1,
                       u16* __restrict__ hseq, u16* __restrict__ H1bf,
                       int* __restrict__ sync) {
  __shared__ float red[4 * 2 * 2 * 16 * 16];   // 16KB
  int* f0 = sync;
  int* f1 = sync + 256 * 128;
  int wg = blockIdx.x;
  if (wg < 128)
    lstm_role<1024, true>(W0T, xp0p, nullptr, hseq, H1bf, f0, f1, red, wg);
  else
    lstm_role<2048, false>(W1T, nullptr, b1, hseq, H1bf, f0, f1, red, wg - 128);
}

// ---------------- softmax finalize: wave-per-row ----------------
__global__ void k_rowfin(const float* __restrict__ pmax, const float* __restrict__ psum,
                         const float* __restrict__ Cl, const int* __restrict__ targets,
                         float* __restrict__ loss) {
  int lane = threadIdx.x & 63, wv = threadIdx.x >> 6;
  int row = blockIdx.x * 4 + wv;
  float mx = -1e30f, s = 0.f;
  if (lane < NCH) { mx = pmax[(size_t)row * NCH + lane]; s = psum[(size_t)row * NCH + lane]; }
  if (lane + 64 < NCH) {
    float m2 = pmax[(size_t)row * NCH + 64 + lane];
    float s2 = psum[(size_t)row * NCH + 64 + lane];
    float M2 = fmaxf(mx, m2);
    s = s * __expf(mx - M2) + s2 * __expf(m2 - M2);
    mx = M2;
  }
#pragma unroll
  for (int d = 1; d < 64; d <<= 1) {
    float mo = __shfl_xor(mx, d, 64);
    float so = __shfl_xor(s, d, 64);
    float M2 = fmaxf(mx, mo);
    s = s * __expf(mx - M2) + so * __expf(mo - M2);
    mx = M2;
  }
  if (lane == 0) {
    float logZ = mx + logf(s);
    int tgt = targets[row];
    float xt = Cl[(size_t)row * V + tgt];
    loss[row] = logZ - xt;
  }
}

__global__ void k_cost(const float* __restrict__ loss, float* __restrict__ out) {
  int tid = threadIdx.x, lane = tid & 63, w = tid >> 6;
  float s = 0.f;
  for (int i = tid; i < BT; i += 256) s += loss[i];
#pragma unroll
  for (int d = 1; d < 64; d <<= 1) s += __shfl_xor(s, d, 64);
  __shared__ float ws4[4];
  if (lane == 0) ws4[w] = s;
  __syncthreads();
  if (tid == 0) out[0] = (ws4[0] + ws4[1] + ws4[2] + ws4[3]) * (1.0f / B);
}

// ---------------- host ----------------
extern "C" void kernel_launch(void* const* d_in, const int* in_sizes, int n_in,
                              void* d_out, int out_size, void* d_ws, size_t ws_size,
                              hipStream_t stream) {
  const int*   input_data = (const int*)d_in[0];
  const int*   targets    = (const int*)d_in[1];
  const float* emb        = (const float*)d_in[2];
  const float* softmax_b  = (const float*)d_in[3];
  const float* W0         = (const float*)d_in[4];
  const float* b0         = (const float*)d_in[5];
  const float* W1         = (const float*)d_in[6];
  const float* b1         = (const float*)d_in[7];
  float* out = (float*)d_out;
  char*  ws  = (char*)d_ws;

  u16*   W0T  = (u16*)(ws + OFF_W0T);
  u16*   W1T  = (u16*)(ws + OFF_W1T);
  u16*   Ebf  = (u16*)(ws + OFF_EBF);
  u16*   Xbf  = (u16*)(ws + OFF_XBF);
  u16*   xp0p = (u16*)(ws + OFF_XP0);
  u16*   H1bf = (u16*)(ws + OFF_H1);
  u16*   hseq = (u16*)(ws + OFF_HSEQ);
  int*   sync = (int*)(ws + OFF_SYNC);
  float* pmax = (float*)(ws + OFF_PMAX);
  float* psum = (float*)(ws + OFF_PSUM);
  float* lossb= (float*)(ws + OFF_LOSS);

  // prep: weight transposes (bf16), embedding convert, X gather, R[0..1]+flags zero
  k_transpose_cvt2<<<dim3(G / 32, 2048 / 32, 2), 256, 0, stream>>>(W0, W0T, W1, W1T);
  k_cvt_bf16<<<2048, 256, 0, stream>>>(emb, Ebf, V * H / 4);
  k_gather_x<<<BT, 256, 0, stream>>>(emb, input_data, Xbf);
  k_zero<<<64, 256, 0, stream>>>((unsigned int*)(ws + OFF_HSEQ), RSTRIDE);  // R[0],R[1]
  k_zero<<<64, 256, 0, stream>>>((unsigned int*)(ws + OFF_SYNC), (int)(SZ_SYNC / 4));

  // xp0p = X @ W0[0:1024,:] + b0  (bf16, block-permuted layout), 256^2 GEMM
  k_gemm256<0><<<dim3(G / 256, BT / 256), 512, 0, stream>>>(
      Xbf, H, W0T, 2048, (float*)xp0p, 0, b0, nullptr, nullptr, 0);

  // persistent pipelined LSTM: flag-sync decoupled chains, weights in VGPRs
  k_lstm_persistent<<<dim3(NWG2), dim3(256), 0, stream>>>(
      W0T, W1T, xp0p, b1, hseq, H1bf, sync);

  // logits = H1 @ E^T + softmax_b, 256^2 3-ring counted-vmcnt GEMM + partials
  k_gemm256<1><<<dim3(V / 256, BT / 256), 512, 0, stream>>>(
      H1bf, H, Ebf, H, out, V, softmax_b, pmax, psum, NCH);

  // per-row logZ + NLL (wave per row), then cost = sum/B appended after logits
  k_rowfin<<<BT / 4, 256, 0, stream>>>(pmax, psum, out, targets, lossb);
  k_cost<<<1, 256, 0, stream>>>(lossb, out + (size_t)BT * V);
}

// Round 12
// 2752.193 us; speedup vs baseline: 1.9248x; 1.0364x over previous
//
#include <hip/hip_runtime.h>
#include <hip/hip_bf16.h>

#define DEV static __device__ __forceinline__

typedef unsigned short u16;
typedef unsigned long long u64;
typedef __attribute__((ext_vector_type(8))) short short8;   // 8 bf16 (4 VGPRs) MFMA frag
typedef __attribute__((ext_vector_type(4))) float f32x4;    // MFMA accumulator

constexpr int V = 32000, H = 1024, B = 32, T = 256;
constexpr int BT = B * T;       // 8192 rows
constexpr int G  = 4 * H;       // 4096 gates
constexpr int NCH = V / 256;    // 125 col-chunks for softmax partials
constexpr int NWG2 = 256;       // persistent LSTM blocks (128 L0 + 128 L1), 1/CU
constexpr int RSTRIDE = 32 * 2048 + 2048;  // u16 per h-buffer (132KB incl 4KB pad)

// ---------------- workspace layout (bytes) ----------------
constexpr size_t SZ_WT    = (size_t)G * 2048 * 2;            // [4096][2048] bf16
constexpr size_t OFF_W0T  = 0;
constexpr size_t OFF_W1T  = OFF_W0T + SZ_WT;
constexpr size_t OFF_EBF  = OFF_W1T + SZ_WT;                 // [32000][1024] bf16
constexpr size_t OFF_XBF  = OFF_EBF + (size_t)V * H * 2;     // [8192][1024] bf16 (row = t*32+b)
constexpr size_t OFF_XP0  = OFF_XBF + (size_t)BT * H * 2;    // bf16 perm [t][wgu][b][q*8+uu]
constexpr size_t OFF_H1   = OFF_XP0 + (size_t)BT * G * 2;    // [8192][1024] bf16 (row = b*256+t)
constexpr size_t OFF_HSEQ = OFF_H1 + (size_t)BT * H * 2;     // R[0..T+1], write-once per tick
constexpr size_t SZ_HSEQ  = (size_t)(T + 2) * RSTRIDE * 2;
constexpr size_t OFF_SYNC = OFF_HSEQ + SZ_HSEQ;              // barrier counters (8KB)
constexpr size_t OFF_PMAX = OFF_SYNC + 8192;                 // [8192][125] f32
constexpr size_t OFF_PSUM = OFF_PMAX + (size_t)BT * NCH * 4;
constexpr size_t OFF_LOSS = OFF_PSUM + (size_t)BT * NCH * 4; // [8192] f32

DEV u16 f2bf(float x) {  // RNE f32 -> bf16 bits
  union { float f; unsigned int u; } v; v.f = x;
  unsigned int r = v.u + 0x7fffu + ((v.u >> 16) & 1u);
  return (u16)(r >> 16);
}
DEV float bf2f(u16 b) {
  union { unsigned int u; float f; } v; v.u = ((unsigned int)b) << 16;
  return v.f;
}
DEV float sigm(float x) { return 1.f / (1.f + expf(-x)); }

DEV void gload_lds16(const u16* g, u16* l) {
  __builtin_amdgcn_global_load_lds(
      (__attribute__((address_space(1))) void*)g,
      (__attribute__((address_space(3))) void*)l, 16, 0, 0);
}

// ---------------- prep kernels ----------------

// batched: z=0 -> W0->W0T, z=1 -> W1->W1T  (f32 [2048][4096] -> bf16 [4096][2048])
__global__ void k_transpose_cvt2(const float* __restrict__ in0, u16* __restrict__ out0,
                                 const float* __restrict__ in1, u16* __restrict__ out1) {
  const float* in = blockIdx.z ? in1 : in0;
  u16* out = blockIdx.z ? out1 : out0;
  __shared__ float tile[32][33];
  int bc = blockIdx.x * 32, br = blockIdx.y * 32;
  int tx = threadIdx.x & 31, ty0 = threadIdx.x >> 5;
#pragma unroll
  for (int i = 0; i < 4; ++i) {
    int ty = ty0 + i * 8;
    tile[ty][tx] = in[(size_t)(br + ty) * G + bc + tx];
  }
  __syncthreads();
#pragma unroll
  for (int i = 0; i < 4; ++i) {
    int ty = ty0 + i * 8;
    out[(size_t)(bc + ty) * 2048 + br + tx] = f2bf(tile[tx][ty]);
  }
}

__global__ void k_cvt_bf16(const float* __restrict__ in, u16* __restrict__ out, int n4) {
  int i = blockIdx.x * blockDim.x + threadIdx.x;
  int stride = gridDim.x * blockDim.x;
  for (; i < n4; i += stride) {
    float4 v = ((const float4*)in)[i];
    ushort4 o;
    o.x = f2bf(v.x); o.y = f2bf(v.y); o.z = f2bf(v.z); o.w = f2bf(v.w);
    ((ushort4*)out)[i] = o;
  }
}

__global__ void k_gather_x(const float* __restrict__ emb, const int* __restrict__ inp,
                           u16* __restrict__ Xbf) {
  int row = blockIdx.x;
  int t = row >> 5, b = row & 31;
  int tok = inp[b * T + t];
  const float4* src = (const float4*)(emb + (size_t)tok * H);
  ushort4* dst = (ushort4*)(Xbf + (size_t)row * H);
  float4 v = src[threadIdx.x];
  ushort4 o;
  o.x = f2bf(v.x); o.y = f2bf(v.y); o.z = f2bf(v.z); o.w = f2bf(v.w);
  dst[threadIdx.x] = o;
}

__global__ void k_zero(unsigned int* __restrict__ p, int nwords) {
  int i = blockIdx.x * blockDim.x + threadIdx.x;
  int stride = gridDim.x * blockDim.x;
  for (; i < nwords; i += stride) p[i] = 0u;
}

// ---------------- 256x256 8-wave counted-vmcnt GEMM ----------------------
// 3-deep LDS ring (96KB): staging tile t+2 never touches a buffer being read.
// vmcnt(4) at tile end; XOR unit-swizzle on both stage-source and frag-read.
// MODE 0: C = permuted bf16 [t][wgu][b][q*8+uu] (xp0 for the LSTM), no softmax.
// MODE 1: C = f32 row-major + bias + online-softmax partials (logits).
constexpr int GNT = 32;  // K-tiles (K=1024)

DEV void stage256(const u16* __restrict__ A, int lda,
                  const u16* __restrict__ Bt, int ldb,
                  int row0, int col0, u16* lds, int t, int h, int tid) {
  int op = h >> 1, hh = h & 1;
  int wid = tid >> 6, lane = tid & 63;
  int r = hh * 128 + wid * 16 + (lane >> 2);
  int k = t * 32 + (((lane & 3) ^ ((lane >> 2) & 3)) << 3);  // XOR unit-swizzle
  const u16* g = (op == 0) ? (A + (size_t)(row0 + r) * lda + k)
                           : (Bt + (size_t)(col0 + r) * ldb + k);
  u16* l = lds + (size_t)((op * 3 + (t % 3)) * 8192 + (hh * 128 + wid * 16) * 32);
  gload_lds16(g, l);
}

template <int MODE>
__global__ __launch_bounds__(512)
void k_gemm256(const u16* __restrict__ A, int lda,
               const u16* __restrict__ Bt, int ldb,
               float* __restrict__ C, int ldc,
               const float* __restrict__ bias,
               float* __restrict__ pmax, float* __restrict__ psum, int nch) {
  __shared__ alignas(16) u16 lds[6 * 8192];   // 96KB: [op(2)][slot(3)][256*32]

  unsigned nwg = gridDim.x * gridDim.y;       // %8==0 required
  unsigned flat = blockIdx.y * gridDim.x + blockIdx.x;
  unsigned nf = (flat & 7) * (nwg >> 3) + (flat >> 3);
  int bx = nf % gridDim.x, by = nf / gridDim.x;
  int row0 = by * 256, col0 = bx * 256;

  int tid = threadIdx.x, lane = tid & 63, wid = tid >> 6;
  int wr = wid >> 2, wc = wid & 3;            // 2M x 4N waves
  int c15 = lane & 15, q4 = lane >> 4;
  int usw = (q4 ^ (c15 & 3)) << 3;            // swizzled unit offset

  f32x4 acc[8][4];
#pragma unroll
  for (int m = 0; m < 8; ++m)
#pragma unroll
    for (int n = 0; n < 4; ++n) acc[m][n] = (f32x4){0.f, 0.f, 0.f, 0.f};

  // prologue: stage tiles 0 and 1
#pragma unroll
  for (int h = 0; h < 4; ++h) stage256(A, lda, Bt, ldb, row0, col0, lds, 0, h, tid);
#pragma unroll
  for (int h = 0; h < 4; ++h) stage256(A, lda, Bt, ldb, row0, col0, lds, 1, h, tid);
  asm volatile("s_waitcnt vmcnt(4)" ::: "memory");   // tile 0 staged
  __builtin_amdgcn_sched_barrier(0);
  __builtin_amdgcn_s_barrier();

  short8 af[4], bfr[4];

  for (int t = 0; t < GNT; ++t) {
    const u16* la = lds + (size_t)(t % 3) * 8192;
    const u16* lb = lds + (size_t)(3 + t % 3) * 8192;

    // ---- phase 0: m 0..3 ----
#pragma unroll
    for (int m = 0; m < 4; ++m)
      af[m] = *(const short8*)(la + (wr * 128 + m * 16 + c15) * 32 + usw);
#pragma unroll
    for (int n = 0; n < 4; ++n)
      bfr[n] = *(const short8*)(lb + (wc * 64 + n * 16 + c15) * 32 + usw);
    if (t + 2 < GNT) {
      stage256(A, lda, Bt, ldb, row0, col0, lds, t + 2, 0, tid);
      stage256(A, lda, Bt, ldb, row0, col0, lds, t + 2, 1, tid);
    }
    __builtin_amdgcn_s_barrier();
    asm volatile("s_waitcnt lgkmcnt(0)" ::: "memory");
    __builtin_amdgcn_sched_barrier(0);
    __builtin_amdgcn_s_setprio(1);
#pragma unroll
    for (int m = 0; m < 4; ++m)
#pragma unroll
      for (int n = 0; n < 4; ++n)
        acc[m][n] = __builtin_amdgcn_mfma_f32_16x16x32_bf16(af[m], bfr[n], acc[m][n], 0, 0, 0);
    __builtin_amdgcn_s_setprio(0);
    __builtin_amdgcn_s_barrier();

    // ---- phase 1: m 4..7 ----
#pragma unroll
    for (int m = 0; m < 4; ++m)
      af[m] = *(const short8*)(la + (wr * 128 + (m + 4) * 16 + c15) * 32 + usw);
    if (t + 2 < GNT) {
      stage256(A, lda, Bt, ldb, row0, col0, lds, t + 2, 2, tid);
      stage256(A, lda, Bt, ldb, row0, col0, lds, t + 2, 3, tid);
    }
    __builtin_amdgcn_s_barrier();
    asm volatile("s_waitcnt lgkmcnt(0)" ::: "memory");
    __builtin_amdgcn_sched_barrier(0);
    __builtin_amdgcn_s_setprio(1);
#pragma unroll
    for (int m = 0; m < 4; ++m)
#pragma unroll
      for (int n = 0; n < 4; ++n)
        acc[m + 4][n] = __builtin_amdgcn_mfma_f32_16x16x32_bf16(af[m], bfr[n], acc[m + 4][n], 0, 0, 0);
    __builtin_amdgcn_s_setprio(0);
    if (t < GNT - 2) {
      asm volatile("s_waitcnt vmcnt(4)" ::: "memory");
      __builtin_amdgcn_sched_barrier(0);
    } else if (t == GNT - 2) {
      asm volatile("s_waitcnt vmcnt(0)" ::: "memory");
      __builtin_amdgcn_sched_barrier(0);
    }
    __builtin_amdgcn_s_barrier();
  }

  // ---- epilogue ----
  float bias_n[4];
#pragma unroll
  for (int n = 0; n < 4; ++n) bias_n[n] = bias[col0 + wc * 64 + n * 16 + c15];

  float2* red = (float2*)lds;   // overlay [256][4] (MODE 1 only)
  __syncthreads();

#pragma unroll
  for (int m = 0; m < 8; ++m) {
#pragma unroll
    for (int jr = 0; jr < 4; ++jr) {
      int rloc = wr * 128 + m * 16 + q4 * 4 + jr;
      int r_g = row0 + rloc;
      float v[4];
#pragma unroll
      for (int n = 0; n < 4; ++n) {
        int c_g = col0 + wc * 64 + n * 16 + c15;
        float val = acc[m][n][jr] + bias_n[n];
        if (MODE == 1) {
          C[(size_t)r_g * ldc + c_g] = val;
        } else {
          // xp0 permuted layout [t][wgu][b][q*8+uu]  (row = t*32+b)
          int tt = r_g >> 5, bb = r_g & 31;
          int q = c_g >> 10, wgup = (c_g & 1023) >> 3, uu = c_g & 7;
          ((u16*)C)[((((size_t)tt * 128 + wgup) * 32 + bb) * 32) + q * 8 + uu] = f2bf(val);
        }
        v[n] = val;
      }
      if (MODE == 1) {
        float mx = fmaxf(fmaxf(v[0], v[1]), fmaxf(v[2], v[3]));
        float s = __expf(v[0] - mx) + __expf(v[1] - mx) + __expf(v[2] - mx) + __expf(v[3] - mx);
#pragma unroll
        for (int d = 1; d < 16; d <<= 1) {
          float mo = __shfl_xor(mx, d, 64);
          float so = __shfl_xor(s, d, 64);
          float M2 = fmaxf(mx, mo);
          s = s * __expf(mx - M2) + so * __expf(mo - M2);
          mx = M2;
        }
        if (c15 == 0) red[rloc * 4 + wc] = make_float2(mx, s);
      }
    }
  }
  if (MODE == 1) {
    __syncthreads();
    if (tid < 256) {
      float M = -1e30f, S = 0.f;
#pragma unroll
      for (int i = 0; i < 4; ++i) {
        float2 a = red[tid * 4 + i];
        float M2 = fmaxf(M, a.x);
        S = S * __expf(M - M2) + a.y * __expf(a.x - M2);
        M = M2;
      }
      pmax[(size_t)(row0 + tid) * nch + bx] = M;
      psum[(size_t)(row0 + tid) * nch + bx] = S;
    }
  }
}

// ---------------- persistent LSTM (round-4 config, best measured 1793us) --
// 256 blocks (128 L0 + 128 L1), weights in VGPRs, coupled layers with ONE
// hierarchical grid barrier per tick: 16 group counters (16 arrivals each)
// -> master (16 arrivals) -> release word; s_sleep(2) poll. Write-once hseq
// buffers: producers store agent-scope, consumers use plain cached loads.

#define RED(w_, bt_, nt_, r_, c_) red[((((w_)*2 + (bt_)) * 2 + (nt_)) * 16 + (r_)) * 16 + (c_)]

DEV void grid_barrier(int* __restrict__ sync, int wg, int gen) {
  __syncthreads();   // drains vmcnt: agent h-stores acked at coherence point
  if (threadIdx.x == 0) {
    int g = wg >> 4;  // 16 groups of 16
    int old = __hip_atomic_fetch_add(sync + g * 64, 1,
                                     __ATOMIC_RELAXED, __HIP_MEMORY_SCOPE_AGENT);
    if (old == 16 * gen - 1) {
      int m = __hip_atomic_fetch_add(sync + 16 * 64, 1,
                                     __ATOMIC_RELAXED, __HIP_MEMORY_SCOPE_AGENT);
      if (m == 16 * gen - 1)
        __hip_atomic_store(sync + 17 * 64, gen,
                           __ATOMIC_RELAXED, __HIP_MEMORY_SCOPE_AGENT);
    }
    while (__hip_atomic_load(sync + 17 * 64,
                             __ATOMIC_RELAXED, __HIP_MEMORY_SCOPE_AGENT) < gen)
      __builtin_amdgcn_s_sleep(2);
  }
  __builtin_amdgcn_sched_barrier(0);
  __syncthreads();
}

template <int KH, bool IS_L0>
DEV void lstm_role(const u16* __restrict__ WT,      // [4096][2048] bf16
                   const u16* __restrict__ xp0p,    // bf16 perm (L0) or null
                   const float* __restrict__ zb1,   // b1 (L1) or null
                   u16* __restrict__ hseq, u16* __restrict__ H1bf,
                   int* __restrict__ sync,
                   float* __restrict__ red, int wgu, int wg) {
  constexpr int KOFF = IS_L0 ? 1024 : 0;   // weight-k offset (h-part of W0)
  constexpr int KS = KH / 4;               // per-wave K slice
  constexpr int NKC = KS / 32;             // k-chunks per wave (8 or 16)
  int tid = threadIdx.x, lane = tid & 63, w = tid >> 6;
  int c15 = lane & 15, q4 = lane >> 4;
  int eb = tid >> 3, eu = tid & 7;         // epilogue identity: (b, unit)

  // ---- preload weight slice into registers (once) ----
  short8 wfr[2][NKC];
#pragma unroll
  for (int nt = 0; nt < 2; ++nt) {
    int lr = nt * 16 + c15;                // local row = gate*8 + unit
    const u16* rp = WT + (size_t)((lr >> 3) * 1024 + wgu * 8 + (lr & 7)) * 2048
                    + KOFF + w * KS + q4 * 8;
#pragma unroll
    for (int kc = 0; kc < NKC; ++kc)
      wfr[nt][kc] = *(const short8*)(rp + kc * 32);
  }

  float zpc[4];
  if (!IS_L0) {
#pragma unroll
    for (int q = 0; q < 4; ++q) zpc[q] = zb1[q * 1024 + wgu * 8 + eu];
  }
  float creg = 0.f;                        // c-state lives in a register

  for (int tick = 0; tick <= T; ++tick) {
    if (IS_L0 ? (tick < T) : (tick >= 1)) {
      int t = tick;
      float zp[4];
      if (IS_L0) {
#pragma unroll
        for (int q = 0; q < 4; ++q)
          zp[q] = bf2f(xp0p[((((size_t)t * 128 + wgu) * 32 + eb) * 32) + q * 8 + eu]);
      } else {
#pragma unroll
        for (int q = 0; q < 4; ++q) zp[q] = zpc[q];
      }

      const u16* hread = hseq + (size_t)t * RSTRIDE;
      f32x4 acc[2][2];
#pragma unroll
      for (int bt = 0; bt < 2; ++bt)
#pragma unroll
        for (int nt = 0; nt < 2; ++nt) acc[bt][nt] = (f32x4){0.f, 0.f, 0.f, 0.f};

#pragma unroll
      for (int kc = 0; kc < NKC; ++kc) {
        int kh = w * KS + kc * 32 + q4 * 8;
        short8 a0 = *(const short8*)(hread + (size_t)c15 * 2048 + kh);
        short8 a1 = *(const short8*)(hread + (size_t)(16 + c15) * 2048 + kh);
        acc[0][0] = __builtin_amdgcn_mfma_f32_16x16x32_bf16(a0, wfr[0][kc], acc[0][0], 0, 0, 0);
        acc[0][1] = __builtin_amdgcn_mfma_f32_16x16x32_bf16(a0, wfr[1][kc], acc[0][1], 0, 0, 0);
        acc[1][0] = __builtin_amdgcn_mfma_f32_16x16x32_bf16(a1, wfr[0][kc], acc[1][0], 0, 0, 0);
        acc[1][1] = __builtin_amdgcn_mfma_f32_16x16x32_bf16(a1, wfr[1][kc], acc[1][1], 0, 0, 0);
      }

      // cross-wave K reduction via LDS
#pragma unroll
      for (int bt = 0; bt < 2; ++bt)
#pragma unroll
        for (int nt = 0; nt < 2; ++nt)
#pragma unroll
          for (int jr = 0; jr < 4; ++jr)
            RED(w, bt, nt, q4 * 4 + jr, c15) = acc[bt][nt][jr];
      __syncthreads();

      // epilogue: thread = (b=eb, unit=eu)
      int bt = eb >> 4, rr = eb & 15;
      float z[4];
#pragma unroll
      for (int q = 0; q < 4; ++q) {
        int lr = q * 8 + eu, nt = lr >> 4, cc = lr & 15;
        z[q] = RED(0, bt, nt, rr, cc) + RED(1, bt, nt, rr, cc) +
               RED(2, bt, nt, rr, cc) + RED(3, bt, nt, rr, cc) + zp[q];
      }
      float gi = sigm(z[0]);
      float gj = tanhf(z[1]);
      float gf = sigm(z[2] + 1.f);   // forget_bias = 1.0
      float go = sigm(z[3]);
      creg = creg * gf + gi * gj;
      float hv = go * tanhf(creg);

      int hb = (int)f2bf(hv);
      int hp = __shfl_xor(hb, 1, 64);  // partner unit (eu^1), same b
      if (!(tid & 1)) {
        unsigned int pack = (unsigned int)(u16)hb | ((unsigned int)(u16)hp << 16);
        u16* hwr = hseq + (size_t)(t + 1) * RSTRIDE + (IS_L0 ? 0 : 1024);
        __hip_atomic_store((unsigned int*)(hwr + (size_t)eb * 2048 + wgu * 8 + eu), pack,
                           __ATOMIC_RELAXED, __HIP_MEMORY_SCOPE_AGENT);
        if (!IS_L0)
          *(unsigned int*)(H1bf + ((size_t)eb * T + (t - 1)) * H + wgu * 8 + eu) = pack;
      }
    }
    grid_barrier(sync, wg, tick + 1);
  }
}

__global__ __launch_bounds__(256, 1)
void k_lstm_persistent(const u16* __restrict__ W0T, const u16* __restrict__ W1T,
                       const u16* __restrict__ xp0p, const float* __restrict__ b1,
                       u16* __restrict__ hseq, u16* __restrict__ H1bf,
                       int* __restrict__ sync) {
  __shared__ float red[4 * 2 * 2 * 16 * 16];   // 16KB
  int wg = blockIdx.x;
  if (wg < 128)
    lstm_role<1024, true>(W0T, xp0p, nullptr, hseq, H1bf, sync, red, wg, wg);
  else
    lstm_role<2048, false>(W1T, nullptr, b1, hseq, H1bf, sync, red, wg - 128, wg);
}

// ---------------- softmax finalize: wave-per-row ----------------
__global__ void k_rowfin(const float* __restrict__ pmax, const float* __restrict__ psum,
                         const float* __restrict__ Cl, const int* __restrict__ targets,
                         float* __restrict__ loss) {
  int lane = threadIdx.x & 63, wv = threadIdx.x >> 6;
  int row = blockIdx.x * 4 + wv;
  float mx = -1e30f, s = 0.f;
  if (lane < NCH) { mx = pmax[(size_t)row * NCH + lane]; s = psum[(size_t)row * NCH + lane]; }
  if (lane + 64 < NCH) {
    float m2 = pmax[(size_t)row * NCH + 64 + lane];
    float s2 = psum[(size_t)row * NCH + 64 + lane];
    float M2 = fmaxf(mx, m2);
    s = s * __expf(mx - M2) + s2 * __expf(m2 - M2);
    mx = M2;
  }
#pragma unroll
  for (int d = 1; d < 64; d <<= 1) {
    float mo = __shfl_xor(mx, d, 64);
    float so = __shfl_xor(s, d, 64);
    float M2 = fmaxf(mx, mo);
    s = s * __expf(mx - M2) + so * __expf(mo - M2);
    mx = M2;
  }
  if (lane == 0) {
    float logZ = mx + logf(s);
    int tgt = targets[row];
    float xt = Cl[(size_t)row * V + tgt];
    loss[row] = logZ - xt;
  }
}

__global__ void k_cost(const float* __restrict__ loss, float* __restrict__ out) {
  int tid = threadIdx.x, lane = tid & 63, w = tid >> 6;
  float s = 0.f;
  for (int i = tid; i < BT; i += 256) s += loss[i];
#pragma unroll
  for (int d = 1; d < 64; d <<= 1) s += __shfl_xor(s, d, 64);
  __shared__ float ws4[4];
  if (lane == 0) ws4[w] = s;
  __syncthreads();
  if (tid == 0) out[0] = (ws4[0] + ws4[1] + ws4[2] + ws4[3]) * (1.0f / B);
}

// ---------------- host ----------------
extern "C" void kernel_launch(void* const* d_in, const int* in_sizes, int n_in,
                              void* d_out, int out_size, void* d_ws, size_t ws_size,
                              hipStream_t stream) {
  const int*   input_data = (const int*)d_in[0];
  const int*   targets    = (const int*)d_in[1];
  const float* emb        = (const float*)d_in[2];
  const float* softmax_b  = (const float*)d_in[3];
  const float* W0         = (const float*)d_in[4];
  const float* b0         = (const float*)d_in[5];
  const float* W1         = (const float*)d_in[6];
  const float* b1         = (const float*)d_in[7];
  float* out = (float*)d_out;
  char*  ws  = (char*)d_ws;

  u16*   W0T  = (u16*)(ws + OFF_W0T);
  u16*   W1T  = (u16*)(ws + OFF_W1T);
  u16*   Ebf  = (u16*)(ws + OFF_EBF);
  u16*   Xbf  = (u16*)(ws + OFF_XBF);
  u16*   xp0p = (u16*)(ws + OFF_XP0);
  u16*   H1bf = (u16*)(ws + OFF_H1);
  u16*   hseq = (u16*)(ws + OFF_HSEQ);
  int*   sync = (int*)(ws + OFF_SYNC);
  float* pmax = (float*)(ws + OFF_PMAX);
  float* psum = (float*)(ws + OFF_PSUM);
  float* lossb= (float*)(ws + OFF_LOSS);

  // prep: weight transposes (bf16), embedding convert, X gather, R[0..1]+sync zero
  k_transpose_cvt2<<<dim3(G / 32, 2048 / 32, 2), 256, 0, stream>>>(W0, W0T, W1, W1T);
  k_cvt_bf16<<<2048, 256, 0, stream>>>(emb, Ebf, V * H / 4);
  k_gather_x<<<BT, 256, 0, stream>>>(emb, input_data, Xbf);
  k_zero<<<64, 256, 0, stream>>>((unsigned int*)(ws + OFF_HSEQ), RSTRIDE);  // R[0],R[1]
  k_zero<<<1, 256, 0, stream>>>((unsigned int*)(ws + OFF_SYNC), 2048);

  // xp0p = X @ W0[0:1024,:] + b0  (bf16, block-permuted layout), 256^2 GEMM
  k_gemm256<0><<<dim3(G / 256, BT / 256), 512, 0, stream>>>(
      Xbf, H, W0T, 2048, (float*)xp0p, 0, b0, nullptr, nullptr, 0);

  // persistent pipelined LSTM: r4 config (hierarchical barrier, coupled layers)
  k_lstm_persistent<<<dim3(NWG2), dim3(256), 0, stream>>>(
      W0T, W1T, xp0p, b1, hseq, H1bf, sync);

  // logits = H1 @ E^T + softmax_b, 256^2 3-ring counted-vmcnt GEMM + partials
  k_gemm256<1><<<dim3(V / 256, BT / 256), 512, 0, stream>>>(
      H1bf, H, Ebf, H, out, V, softmax_b, pmax, psum, NCH);

  // per-row logZ + NLL (wave per row), then cost = sum/B appended after logits
  k_rowfin<<<BT / 4, 256, 0, stream>>>(pmax, psum, out, targets, lossb);
  k_cost<<<1, 256, 0, stream>>>(lossb, out + (size_t)BT * V);
}